// Round 14
// baseline (715.995 us; speedup 1.0000x reference)
//
#include <hip/hip_runtime.h>
#include <hip/hip_bf16.h>

typedef __hip_bfloat16 bf16;

#define BB 8
#define NN 2048
#define CC 9
#define KK 20
#define NSLOT 32

// ---------------- ws layout (float elements) ----------------
static constexpr int OFF_X1   = 0;               // 1048576 (16384x64 fp32)
static constexpr int OFF_X2   = 1048576;         // 1048576
static constexpr int OFF_X3   = 2097152;         // 1048576
static constexpr int OFF_SQN  = 3145728;         // 16384
static constexpr int OFF_GMAX = 3162112;         // 8192
static constexpr int OFF_PART = 3170304;         // 262144 (PART 131072 | C7 4096 | SLOTS 40960)
static constexpr int OFF_STATS= 3432448;         // 12800 (4224 doubles + 4224 floats)
static constexpr int OFF_IDX  = 3445248;         // 327680 (int32)
static constexpr int BASE_END = 3772928;         // 15.1 MB
// SLOTS: slot-spread double stats for the 64-ch layers (L0..L4), 32x less L2-line contention.
// BASE_END region (lifetimes disjoint): GRAM1 fp32 16MB (knn stages) | H7 (layer 7+)
// r8:  LDS strides for float4 access MUST be 0 mod 4 dwords.
// r9:  triangle-gram mirror writes (lane-scattered) lose to full coalesced gram.
// r11: shrinking per-thread acc lets the compiler pipeline into VGPR=256. 128x128 gram only.
// r13/r14: finalize fusion is worth it ONLY for low-block-count consumers (bnact 1024,
//      gmax_fin 32). In 4096-block edgegemm the per-block 32KB slot re-read costs
//      128MB L2/dispatch (+6.7us) > the saved dispatch. Edgegemm takes sc/sh.

typedef __attribute__((ext_vector_type(8))) short bf16x8;
typedef __attribute__((ext_vector_type(4))) float f32x4;

__device__ __forceinline__ float lrelu(float x){ return x >= 0.f ? x : 0.2f * x; }

__device__ __forceinline__ void store4(float* p, float a, float b, float c, float d){
    *(float4*)p = make_float4(a,b,c,d);
}
__device__ __forceinline__ void store4(bf16* p, float a, float b, float c, float d){
    union { bf16 h[4]; uint2 u; } pk;
    pk.h[0] = (bf16)a; pk.h[1] = (bf16)b; pk.h[2] = (bf16)c; pk.h[3] = (bf16)d;
    *(uint2*)p = pk.u;
}

// 2-way bf16 split: v = h + l to ~2^-16 relative
__device__ __forceinline__ void split2b(float v, bf16 &h, bf16 &l){
    h = (bf16)v;
    l = (bf16)(v - (float)h);
}

// float -> order-preserving uint32
__device__ __forceinline__ unsigned f2sort(float f){
    unsigned b = __float_as_uint(f);
    return b ^ (unsigned)(((int)b >> 31) | (int)0x80000000);
}

// per-block BN finalize for the 64-ch slot-spread layers: arithmetic identical
// to k_finalize (same double exprs, same slot loop order) -> identical floats.
__device__ __forceinline__ void blk_fin64(const double* __restrict__ dsum,
                                          const double* __restrict__ dssq,
                                          const float* __restrict__ g, const float* __restrict__ b,
                                          float* lsc, float* lsh, int tid){
    const double inv_cnt = 1.0 / (double)(BB*NN*KK);
    if (tid < 64){
        int c = tid;
        double sm = 0.0, sq = 0.0;
        for (int s = 0; s < NSLOT; s++){ sm += dsum[s*64 + c]; sq += dssq[s*64 + c]; }
        double m = sm * inv_cnt;
        double v = sq * inv_cnt - m*m;
        if (v < 0.0) v = 0.0;
        float rs = (float)(1.0 / sqrt(v + 1e-5));
        float sc = g[c] * rs;
        lsc[c] = sc;
        lsh[c] = b[c] - (float)m*sc;
    }
}

// exact fallback: 20x argmax-extract (desc value, asc index) — rare path
__device__ __forceinline__ void fallback_extract(unsigned (&u)[32], int lane, int* __restrict__ orow){
    for (int it = 0; it < KK; it++){
        unsigned bv = u[0]; int bj = 0;
        #pragma unroll
        for (int j = 1; j < 32; j++) if (u[j] > bv){ bv = u[j]; bj = j; }
        int bm = bj*64 + lane;
        #pragma unroll
        for (int off = 32; off >= 1; off >>= 1){
            unsigned ov = __shfl_xor(bv, off);
            int om = __shfl_xor(bm, off);
            if (ov > bv || (ov == bv && om < bm)){ bv = ov; bm = om; }
        }
        if (lane == 0) orow[it] = bm;
        if ((bm & 63) == lane) u[bm >> 6] = 0u;
    }
}

// ---------------- exact top-20 (largest) of 2048 candidates, one wave ----------------
__device__ __forceinline__ void topk20(unsigned (&u)[32], int lane,
                                       unsigned* sval, unsigned* sidx, int* __restrict__ orow){
    unsigned mx = 0u;
    #pragma unroll
    for (int j = 0; j < 32; j++) mx = (u[j] > mx) ? u[j] : mx;
    unsigned v = ~mx;
    #pragma unroll
    for (int k = 2; k <= 64; k <<= 1){
        #pragma unroll
        for (int j = k >> 1; j > 0; j >>= 1){
            unsigned o = __shfl_xor(v, j);
            bool keepMin = ((lane & k) == 0) == ((lane & j) == 0);
            bool less = (o < v);
            v = (keepMin == less) ? o : v;
        }
    }
    unsigned t0 = ~__shfl(v, 19);
    unsigned mask = 0u;
    #pragma unroll
    for (int j = 0; j < 32; j++) if (u[j] >= t0) mask |= (1u << j);
    int cnt = __popc(mask);
    int incl = cnt;
    #pragma unroll
    for (int off = 1; off < 64; off <<= 1){
        int t = __shfl_up(incl, off);
        if (lane >= off) incl += t;
    }
    int total = __shfl(incl, 63);
    if (total <= 64){
        int slot = incl - cnt;
        unsigned mm = mask;
        while (mm){
            int j = __ffs(mm) - 1;
            mm &= mm - 1u;
            sval[slot] = u[j];
            sidx[slot] = (unsigned)(j*64 + lane);
            slot++;
        }
        __threadfence_block();
        unsigned long long c = ~0ULL;
        if (lane < total)
            c = (((unsigned long long)(~sval[lane])) << 32) | (unsigned long long)sidx[lane];
        #pragma unroll
        for (int k = 2; k <= 64; k <<= 1){
            #pragma unroll
            for (int j = k >> 1; j > 0; j >>= 1){
                unsigned long long o = __shfl_xor(c, j);
                bool keepMin = ((lane & k) == 0) == ((lane & j) == 0);
                bool less = (o < c);
                c = (keepMin == less) ? o : c;
            }
        }
        if (lane < KK) orow[lane] = (int)(c & 0xffffffffULL);
    } else {
        fallback_extract(u, lane, orow);
    }
}

// ---------------- K0: echo (B,C,N) -> (B,N,C) fp32 ----------------
__global__ void k_echo(const float* __restrict__ x, float* __restrict__ out0){
    int t = blockIdx.x * 256 + threadIdx.x;
    if (t >= BB*CC*NN) return;
    int b = t / (CC*NN); int r = t % (CC*NN); int c = r / NN; int n = r % NN;
    out0[(b*NN + n)*CC + c] = x[t];
}

// ---------------- K1: knn on 3-d coords ----------------
__global__ __launch_bounds__(256) void k_knn3(const float* __restrict__ x, int* __restrict__ idx){
    __shared__ float crd[NN*3];
    __shared__ unsigned sval[4*64];
    __shared__ unsigned sidx[4*64];
    int b  = blockIdx.x / (NN/4);
    int rb = blockIdx.x % (NN/4);
    for (int c = 0; c < 3; c++)
        for (int p = threadIdx.x; p < NN; p += 256)
            crd[p*3 + c] = x[(b*CC + 6 + c)*NN + p];
    __syncthreads();
    int lane = threadIdx.x & 63;
    int wid  = threadIdx.x >> 6;
    int n = rb*4 + wid;
    float qx = crd[n*3], qy = crd[n*3+1], qz = crd[n*3+2];
    float sqn = qx*qx + qy*qy + qz*qz;
    unsigned u[32];
    #pragma unroll
    for (int j = 0; j < 32; j++){
        int m = j*64 + lane;
        float mx = crd[m*3], my = crd[m*3+1], mz = crd[m*3+2];
        float d = 2.f*(qx*mx + qy*my + qz*mz) - sqn - (mx*mx + my*my + mz*mz);
        u[j] = f2sort(d);
    }
    topk20(u, lane, sval + wid*64, sidx + wid*64, idx + (b*NN + n)*KK);
}

// ---------------- P/Q stage 1: 32-row blocks ----------------
__global__ __launch_bounds__(256) void k_pq9(const float* __restrict__ x, const float* __restrict__ w,
                                             float* __restrict__ P, float* __restrict__ Q){
    __shared__ __align__(16) float Xs[32*16];
    __shared__ __align__(16) float Wp[12*68];
    __shared__ __align__(16) float Wq[12*68];
    int row0 = blockIdx.x * 32;
    int b  = row0 >> 11;
    int n0 = row0 & (NN-1);
    int tx = threadIdx.x & 15, ty = threadIdx.x >> 4;
    for (int i = threadIdx.x; i < 32*12; i += 256){
        int r = i & 31, c = i >> 5;
        Xs[r*16 + c] = (c < 9) ? x[(b*CC + c)*NN + n0 + r] : 0.f;
    }
    for (int i = threadIdx.x; i < 64*12; i += 256){
        int c = i % 12, o = i / 12;
        float a = 0.f, dd = 0.f;
        if (c < 9){
            a  = w[o*18 + c];
            dd = w[o*18 + 9 + c] - a;
        }
        Wp[c*68 + o] = a;
        Wq[c*68 + o] = dd;
    }
    __syncthreads();
    float ap[2][4] = {{0.f}}, aq[2][4] = {{0.f}};
    for (int c0 = 0; c0 < 12; c0 += 4){
        float wp4[16], wq4[16];
        #pragma unroll
        for (int q = 0; q < 4; q++){
            *(float4*)&wp4[q*4] = *(const float4*)&Wp[(c0 + q)*68 + tx*4];
            *(float4*)&wq4[q*4] = *(const float4*)&Wq[(c0 + q)*68 + tx*4];
        }
        #pragma unroll
        for (int ii = 0; ii < 2; ii++){
            float4 x4 = *(const float4*)&Xs[(ty*2 + ii)*16 + c0];
            #pragma unroll
            for (int jj = 0; jj < 4; jj++){
                ap[ii][jj] += x4.x*wp4[jj] + x4.y*wp4[4+jj] + x4.z*wp4[8+jj] + x4.w*wp4[12+jj];
                aq[ii][jj] += x4.x*wq4[jj] + x4.y*wq4[4+jj] + x4.z*wq4[8+jj] + x4.w*wq4[12+jj];
            }
        }
    }
    #pragma unroll
    for (int ii = 0; ii < 2; ii++){
        int row = row0 + ty*2 + ii;
        store4(&P[row*64 + tx*4], ap[ii][0], ap[ii][1], ap[ii][2], ap[ii][3]);
        store4(&Q[row*64 + tx*4], aq[ii][0], aq[ii][1], aq[ii][2], aq[ii][3]);
    }
}

// ---------------- P/Q stages 2/3: 32-row blocks ----------------
__global__ __launch_bounds__(256) void k_pq64(const float* __restrict__ X, const float* __restrict__ w,
                                              float* __restrict__ P, float* __restrict__ Q){
    __shared__ __align__(16) float Xs[32*68];
    __shared__ __align__(16) float Wp[64*68];
    __shared__ __align__(16) float Wq[64*68];
    int row0 = blockIdx.x * 32;
    int tx = threadIdx.x & 15, ty = threadIdx.x >> 4;
    for (int i = threadIdx.x; i < 32*64; i += 256){
        int c = i & 63, r = i >> 6;
        Xs[r*68 + c] = X[(row0 + r)*64 + c];
    }
    for (int i = threadIdx.x; i < 64*64; i += 256){
        int c = i & 63, o = i >> 6;
        float a  = w[o*128 + c];
        Wp[c*68 + o] = a;
        Wq[c*68 + o] = w[o*128 + 64 + c] - a;
    }
    __syncthreads();
    float ap[2][4] = {{0.f}}, aq[2][4] = {{0.f}};
    for (int c0 = 0; c0 < 64; c0 += 4){
        float wp4[16], wq4[16];
        #pragma unroll
        for (int q = 0; q < 4; q++){
            *(float4*)&wp4[q*4] = *(const float4*)&Wp[(c0 + q)*68 + tx*4];
            *(float4*)&wq4[q*4] = *(const float4*)&Wq[(c0 + q)*68 + tx*4];
        }
        #pragma unroll
        for (int ii = 0; ii < 2; ii++){
            float4 x4 = *(const float4*)&Xs[(ty*2 + ii)*68 + c0];
            #pragma unroll
            for (int jj = 0; jj < 4; jj++){
                ap[ii][jj] += x4.x*wp4[jj] + x4.y*wp4[4+jj] + x4.z*wp4[8+jj] + x4.w*wp4[12+jj];
                aq[ii][jj] += x4.x*wq4[jj] + x4.y*wq4[4+jj] + x4.z*wq4[8+jj] + x4.w*wq4[12+jj];
            }
        }
    }
    #pragma unroll
    for (int ii = 0; ii < 2; ii++){
        int row = row0 + ty*2 + ii;
        store4(&P[row*64 + tx*4], ap[ii][0], ap[ii][1], ap[ii][2], ap[ii][3]);
        store4(&Q[row*64 + tx*4], aq[ii][0], aq[ii][1], aq[ii][2], aq[ii][3]);
    }
}

// ---------------- PASS A: stats of h = P[j]+Q[n]; optional fused max-over-k ----------------
template<bool DOMAX>
__global__ __launch_bounds__(256) void k_hstats(const float* __restrict__ P, const float* __restrict__ Q,
                                                const int* __restrict__ nbr, float* __restrict__ Xraw,
                                                double* __restrict__ dsum, double* __restrict__ dssq){
    __shared__ float sbuf[16*64];
    __shared__ float qbuf[16*64];
    int row0 = blockIdx.x * 80;
    int slot = blockIdx.x & (NSLOT-1);
    int tx = threadIdx.x & 15, ty = threadIdx.x >> 4;
    int ng = (row0 + ty*5) / 20;
    int b  = ng >> 11;
    float4 q4 = *(const float4*)&Q[ng*64 + tx*4];
    float s[4] = {0.f,0.f,0.f,0.f}, s2[4] = {0.f,0.f,0.f,0.f};
    float m[4] = {-INFINITY,-INFINITY,-INFINITY,-INFINITY};
    #pragma unroll
    for (int ii = 0; ii < 5; ii++){
        int e = row0 + ty*5 + ii;
        int j = nbr[e];
        float4 p4 = *(const float4*)&P[((b << 11) + j)*64 + tx*4];
        float h0 = p4.x + q4.x, h1 = p4.y + q4.y, h2 = p4.z + q4.z, h3 = p4.w + q4.w;
        s[0] += h0; s[1] += h1; s[2] += h2; s[3] += h3;
        s2[0] += h0*h0; s2[1] += h1*h1; s2[2] += h2*h2; s2[3] += h3*h3;
        if (DOMAX){
            m[0] = fmaxf(m[0], h0); m[1] = fmaxf(m[1], h1);
            m[2] = fmaxf(m[2], h2); m[3] = fmaxf(m[3], h3);
        }
    }
    #pragma unroll
    for (int jj = 0; jj < 4; jj++){
        sbuf[ty*64 + tx*4 + jj] = s[jj];
        qbuf[ty*64 + tx*4 + jj] = s2[jj];
    }
    if (DOMAX){
        #pragma unroll
        for (int off = 32; off >= 16; off >>= 1){
            #pragma unroll
            for (int jj = 0; jj < 4; jj++) m[jj] = fmaxf(m[jj], __shfl_xor(m[jj], off));
        }
        int lane = threadIdx.x & 63;
        if (lane < 16){
            int pi = ty >> 2;
            store4(&Xraw[(row0/20 + pi)*64 + tx*4], m[0], m[1], m[2], m[3]);
        }
    }
    __syncthreads();
    if (threadIdx.x < 64){
        double t = 0.0;
        #pragma unroll
        for (int k = 0; k < 16; k++) t += (double)sbuf[k*64 + threadIdx.x];
        atomicAdd(&dsum[slot*64 + threadIdx.x], t);
    } else if (threadIdx.x < 128){
        int c = threadIdx.x - 64;
        double t = 0.0;
        #pragma unroll
        for (int k = 0; k < 16; k++) t += (double)qbuf[k*64 + c];
        atomicAdd(&dssq[slot*64 + c], t);
    }
}

// ---------------- PASS B: edge GEMM, fused stats + max-over-k (r12 form) ----------------
// Takes precomputed sc/sh (r14: per-block finalize in 4096 blocks costs 128MB
// L2/dispatch — worse than the tiny finalize dispatch it replaced).
__global__ __launch_bounds__(256) void k_edgegemm(const float* __restrict__ P, const float* __restrict__ Q,
                                                  const int* __restrict__ nbr,
                                                  const float* __restrict__ sc, const float* __restrict__ sh,
                                                  const float* __restrict__ w,
                                                  float* __restrict__ Xraw,
                                                  double* __restrict__ dsum, double* __restrict__ dssq){
    __shared__ __align__(16) float Fs[80*68];
    __shared__ __align__(16) float Ws[64*68];
    int row0 = blockIdx.x * 80;
    int slot = blockIdx.x & (NSLOT-1);
    int tx = threadIdx.x & 15, ty = threadIdx.x >> 4;
    // ---- stage F: gather + bn + lrelu, float4 wide ----
    {
        int c4 = threadIdx.x & 15;
        float4 scv = *(const float4*)&sc[c4*4];
        float4 shv = *(const float4*)&sh[c4*4];
        for (int i = threadIdx.x; i < 80*16; i += 256){
            int r  = i >> 4;
            int e  = row0 + r;
            int ng = e / 20;
            int b  = ng >> 11;
            int j  = nbr[e];
            float4 p4 = *(const float4*)&P[((b << 11) + j)*64 + c4*4];
            float4 q4 = *(const float4*)&Q[ng*64 + c4*4];
            float4 f4;
            f4.x = lrelu((p4.x + q4.x)*scv.x + shv.x);
            f4.y = lrelu((p4.y + q4.y)*scv.y + shv.y);
            f4.z = lrelu((p4.z + q4.z)*scv.z + shv.z);
            f4.w = lrelu((p4.w + q4.w)*scv.w + shv.w);
            *(float4*)&Fs[r*68 + c4*4] = f4;
        }
    }
    for (int i = threadIdx.x; i < 64*16; i += 256){
        int o = i >> 4, c4 = i & 15;
        float4 w4 = *(const float4*)&w[o*64 + c4*4];
        Ws[(c4*4+0)*68 + o] = w4.x;
        Ws[(c4*4+1)*68 + o] = w4.y;
        Ws[(c4*4+2)*68 + o] = w4.z;
        Ws[(c4*4+3)*68 + o] = w4.w;
    }
    __syncthreads();
    float acc[5][4] = {{0.f}};
    for (int c0 = 0; c0 < 64; c0 += 4){
        float bb4[16];
        #pragma unroll
        for (int q = 0; q < 4; q++)
            *(float4*)&bb4[q*4] = *(const float4*)&Ws[(c0 + q)*68 + tx*4];
        #pragma unroll
        for (int ii = 0; ii < 5; ii++){
            float4 a4 = *(const float4*)&Fs[(ty*5 + ii)*68 + c0];
            #pragma unroll
            for (int jj = 0; jj < 4; jj++)
                acc[ii][jj] += a4.x*bb4[jj] + a4.y*bb4[4+jj] + a4.z*bb4[8+jj] + a4.w*bb4[12+jj];
        }
    }
    // stats into registers
    float s[4], q2[4], m[4];
    #pragma unroll
    for (int jj = 0; jj < 4; jj++){
        s[jj]  = acc[0][jj] + acc[1][jj] + acc[2][jj] + acc[3][jj] + acc[4][jj];
        q2[jj] = acc[0][jj]*acc[0][jj] + acc[1][jj]*acc[1][jj] + acc[2][jj]*acc[2][jj]
               + acc[3][jj]*acc[3][jj] + acc[4][jj]*acc[4][jj];
        m[jj]  = fmaxf(fmaxf(fmaxf(acc[0][jj], acc[1][jj]), fmaxf(acc[2][jj], acc[3][jj])), acc[4][jj]);
    }
    __syncthreads();             // all waves done reading Fs -> safe to alias
    float* sbuf = Fs;
    float* qbuf = Fs + 1024;
    #pragma unroll
    for (int jj = 0; jj < 4; jj++){
        sbuf[ty*64 + tx*4 + jj] = s[jj];
        qbuf[ty*64 + tx*4 + jj] = q2[jj];
    }
    #pragma unroll
    for (int off = 32; off >= 16; off >>= 1){
        #pragma unroll
        for (int jj = 0; jj < 4; jj++) m[jj] = fmaxf(m[jj], __shfl_xor(m[jj], off));
    }
    int lane = threadIdx.x & 63;
    if (lane < 16){
        int pi = ty >> 2;
        store4(&Xraw[(row0/20 + pi)*64 + tx*4], m[0], m[1], m[2], m[3]);
    }
    __syncthreads();
    if (threadIdx.x < 64){
        double t = 0.0;
        #pragma unroll
        for (int k = 0; k < 16; k++) t += (double)sbuf[k*64 + threadIdx.x];
        atomicAdd(&dsum[slot*64 + threadIdx.x], t);
    } else if (threadIdx.x < 128){
        int c = threadIdx.x - 64;
        double t = 0.0;
        #pragma unroll
        for (int k = 0; k < 16; k++) t += (double)qbuf[k*64 + c];
        atomicAdd(&dssq[slot*64 + c], t);
    }
}

// ---------------- BN finalize (L0/L2 slot-spread + L6/L7) ----------------
__global__ void k_finalize(const double* __restrict__ dsum, const double* __restrict__ dssq,
                           const float* __restrict__ g, const float* __restrict__ b,
                           float* __restrict__ scale, float* __restrict__ shift,
                           int ch, double inv_cnt, int nslot){
    int c = blockIdx.x*256 + threadIdx.x;
    if (c >= ch) return;
    double sm = 0.0, sq = 0.0;
    for (int s = 0; s < nslot; s++){
        sm += dsum[s*ch + c];
        sq += dssq[s*ch + c];
    }
    double m = sm * inv_cnt;
    double v = sq * inv_cnt - m*m;
    if (v < 0.0) v = 0.0;
    float rs = (float)(1.0 / sqrt(v + 1e-5));
    float sc = g[c] * rs;
    scale[c] = sc;
    shift[c] = b[c] - (float)m*sc;
}

// ---------------- in-place bn+lrelu on (16384 x 64), float4, fused finalize ----------------
__global__ void k_bnact(float* __restrict__ X,
                        const double* __restrict__ dsum, const double* __restrict__ dssq,
                        const float* __restrict__ g, const float* __restrict__ b){
    __shared__ __align__(16) float lsc[64];
    __shared__ __align__(16) float lsh[64];
    blk_fin64(dsum, dssq, g, b, lsc, lsh, threadIdx.x);
    __syncthreads();
    int t = blockIdx.x*256 + threadIdx.x;
    int e0 = t*4;
    int c0 = e0 & 63;
    float4 v = *(float4*)&X[e0];
    v.x = lrelu(v.x*lsc[c0+0] + lsh[c0+0]);
    v.y = lrelu(v.y*lsc[c0+1] + lsh[c0+1]);
    v.z = lrelu(v.z*lsc[c0+2] + lsh[c0+2]);
    v.w = lrelu(v.w*lsc[c0+3] + lsh[c0+3]);
    *(float4*)&X[e0] = v;
}

// ---------------- in-place bn8+lrelu on out1 (B,256,N), float4 ----------------
__global__ void k_bnact8(float* __restrict__ O, const float* __restrict__ sc, const float* __restrict__ sh){
    int t = blockIdx.x*256 + threadIdx.x;
    int e0 = t*4;
    int oc = (e0 >> 11) & 255;
    float s = sc[oc], h = sh[oc];
    float4 v = *(float4*)&O[e0];
    v.x = lrelu(v.x*s + h);
    v.y = lrelu(v.y*s + h);
    v.z = lrelu(v.z*s + h);
    v.w = lrelu(v.w*s + h);
    *(float4*)&O[e0] = v;
}

// ---------------- per-row squared norm ----------------
__global__ void k_sqnorm(const float* __restrict__ X, float* __restrict__ sqn){
    int row  = blockIdx.x*4 + (threadIdx.x >> 6);
    int lane = threadIdx.x & 63;
    float v = X[row*64 + lane];
    float s = v*v;
    #pragma unroll
    for (int off = 32; off >= 1; off >>= 1) s += __shfl_xor(s, off);
    if (lane == 0) sqn[row] = s;
}

// ---------------- Gram, up to 2 batches per dispatch: 128x128 tile, 8x8/thread ----------------
__global__ __launch_bounds__(256) void k_gram2(const float* __restrict__ X, float* G0, float* G1, int b0){
    __shared__ __align__(16) float As[32*132];
    __shared__ __align__(16) float Bs[32*132];
    int sub = blockIdx.x >> 8;
    int t   = blockIdx.x & 255;
    const float* Xb = X + (size_t)(b0 + sub)*NN*64;
    float* gram = sub ? G1 : G0;
    int tr = t >> 4, tc = t & 15;
    int tx = threadIdx.x & 15, ty = threadIdx.x >> 4;
    float acc[8][8];
    #pragma unroll
    for (int i = 0; i < 8; i++)
        #pragma unroll
        for (int j = 0; j < 8; j++) acc[i][j] = 0.f;
    for (int kc0 = 0; kc0 < 64; kc0 += 32){
        __syncthreads();
        for (int i = threadIdx.x; i < 128*32; i += 256){
            int k = i & 31, r = i >> 5;
            As[k*132 + r] = Xb[(tr*128 + r)*64 + kc0 + k];
            Bs[k*132 + r] = Xb[(tc*128 + r)*64 + kc0 + k];
        }
        __syncthreads();
        for (int k = 0; k < 32; k++){
            float4 a0 = *(const float4*)&As[k*132 + ty*8];
            float4 a1 = *(const float4*)&As[k*132 + ty*8 + 4];
            float4 b0v = *(const float4*)&Bs[k*132 + tx*8];
            float4 b1v = *(const float4*)&Bs[k*132 + tx*8 + 4];
            float av[8] = {a0.x,a0.y,a0.z,a0.w,a1.x,a1.y,a1.z,a1.w};
            float bv[8] = {b0v.x,b0v.y,b0v.z,b0v.w,b1v.x,b1v.y,b1v.z,b1v.w};
            #pragma unroll
            for (int i = 0; i < 8; i++)
                #pragma unroll
                for (int j = 0; j < 8; j++) acc[i][j] += av[i]*bv[j];
        }
    }
    #pragma unroll
    for (int i = 0; i < 8; i++){
        int row = tr*128 + ty*8 + i;
        *(float4*)&gram[(size_t)row*NN + tc*128 + tx*8]     = make_float4(acc[i][0],acc[i][1],acc[i][2],acc[i][3]);
        *(float4*)&gram[(size_t)row*NN + tc*128 + tx*8 + 4] = make_float4(acc[i][4],acc[i][5],acc[i][6],acc[i][7]);
    }
}

// ---------------- top-20 from gram rows, up to 2 batches per dispatch ----------------
__global__ __launch_bounds__(256) void k_sel2(const float* G0, const float* G1,
                                              const float* __restrict__ sqn, int* __restrict__ idx){
    __shared__ unsigned sval[4*64];
    __shared__ unsigned sidx[4*64];
    int sub = blockIdx.x >> 9;
    int rb  = blockIdx.x & 511;
    const float* gram = sub ? G1 : G0;
    const float* sq   = sqn + sub*NN;
    int lane = threadIdx.x & 63;
    int wid  = threadIdx.x >> 6;
    int n = rb*4 + wid;
    const float* grow = gram + (size_t)n*NN;
    float sn = sq[n];
    unsigned u[32];
    #pragma unroll
    for (int j = 0; j < 32; j++){
        int m = j*64 + lane;
        u[j] = f2sort(2.f*grow[m] - sn - sq[m]);
    }
    topk20(u, lane, sval + wid*64, sidx + wid*64, idx + (sub*NN + n)*KK);
}

// ---------------- C7 precompute ----------------
__global__ __launch_bounds__(256) void k_c7(const float* __restrict__ gmax, const float* __restrict__ w7,
                                            float* __restrict__ C7){
    __shared__ float red[4*8];
    int oc = blockIdx.x;
    int tid = threadIdx.x, lane = tid & 63, wid = tid >> 6;
    float a[8];
    #pragma unroll
    for (int b = 0; b < 8; b++) a[b] = 0.f;
    for (int k = tid; k < 1024; k += 256){
        float wv = w7[oc*1216 + k];
        #pragma unroll
        for (int b = 0; b < 8; b++) a[b] += gmax[b*1024 + k] * wv;
    }
    #pragma unroll
    for (int b = 0; b < 8; b++){
        #pragma unroll
        for (int off = 32; off >= 1; off >>= 1) a[b] += __shfl_xor(a[b], off);
        if (lane == 0) red[wid*8 + b] = a[b];
    }
    __syncthreads();
    if (tid < 8){
        float s = red[tid] + red[8 + tid] + red[16 + tid] + red[24 + tid];
        C7[tid*512 + oc] = s;
    }
}

// ---------------- unified head GEMM: per-mode tile, bf16x3 MFMA ----------------
// MODE2: 128x128   MODE3: 128x64   MODE4: 64x64  (all 1024 blocks = 4/CU)
template<int MODE, bool MAXN, int STMODE, typename TST, typename TH7>
__global__ __launch_bounds__(256) void k_head(
    const float* __restrict__ X1, const float* __restrict__ X2, const float* __restrict__ X3,
    const TH7*  __restrict__ H7, const float* __restrict__ C7,
    const float* __restrict__ sc_in, const float* __restrict__ sh_in,
    const float* __restrict__ w,
    TST* __restrict__ HST, float* __restrict__ out1t, float* __restrict__ part,
    double* __restrict__ dsum, double* __restrict__ dssq)
{
    constexpr int CIN  = (MODE == 4) ? 512 : 192;
    constexpr int WST  = (MODE == 2) ? 192 : (MODE == 3 ? 1216 : 512);
    constexpr int WOFF = (MODE == 3) ? 1024 : 0;
    constexpr int COUT = (MODE == 2) ? 1024 : (MODE == 3 ? 512 : 256);
    constexpr int BM   = (MODE == 4) ? 64 : 128;
    constexpr int BN   = (MODE == 2) ? 128 : 64;
    constexpr int LOG2NRT = (BM == 64) ? 8 : 7;     // 16384/BM row tiles
    constexpr int RT2  = BM/64;                      // row frags per wave
    constexpr int C2   = BN/16;                      // col frags per wave
    constexpr int RPW  = BM/4;                       // rows per wave
    __shared__ __align__(16) char smem[(BM+BN)*128];
    constexpr int AH = 0, AL = BM*64, BH = 2*BM*64, BL = 2*BM*64 + BN*64;
    int tid = threadIdx.x;
    int rt = blockIdx.x & ((1 << LOG2NRT) - 1);
    int ct = blockIdx.x >> LOG2NRT;
    int row0 = rt * BM;
    int col0 = ct * BN;
    int b = row0 >> 11;
    int wv = tid >> 6, l = tid & 63;
    int rl = l & 15, g = l >> 4;

    f32x4 acc[RT2][C2];
    #pragma unroll
    for (int i = 0; i < RT2; i++)
        #pragma unroll
        for (int j = 0; j < C2; j++) acc[i][j] = (f32x4){0.f,0.f,0.f,0.f};

    for (int s = 0; s < CIN/32; s++){
        int cg0 = s*32;
        __syncthreads();
        // ---- stage A (BM rows x 32 k), 8 elems/thread/iter ----
        #pragma unroll
        for (int it = 0; it < BM/64; it++){
            int i = tid + it*256;
            int r = i >> 2, kg = i & 3;
            float v[8];
            if (MODE == 4){
                float4 s0 = *(const float4*)&sc_in[cg0 + kg*8];
                float4 s1 = *(const float4*)&sc_in[cg0 + kg*8 + 4];
                float4 h0 = *(const float4*)&sh_in[cg0 + kg*8];
                float4 h1 = *(const float4*)&sh_in[cg0 + kg*8 + 4];
                float ss[8] = {s0.x,s0.y,s0.z,s0.w,s1.x,s1.y,s1.z,s1.w};
                float hh[8] = {h0.x,h0.y,h0.z,h0.w,h1.x,h1.y,h1.z,h1.w};
                if constexpr (sizeof(TH7) == 2){
                    union { uint4 q; unsigned short us[8]; } raw;
                    raw.q = *(const uint4*)&H7[(size_t)(row0 + r)*512 + cg0 + kg*8];
                    #pragma unroll
                    for (int e = 0; e < 8; e++)
                        v[e] = lrelu(__uint_as_float((unsigned)raw.us[e] << 16)*ss[e] + hh[e]);
                } else {
                    float4 a0 = *(const float4*)&H7[(size_t)(row0 + r)*512 + cg0 + kg*8];
                    float4 a1 = *(const float4*)&H7[(size_t)(row0 + r)*512 + cg0 + kg*8 + 4];
                    float av[8] = {a0.x,a0.y,a0.z,a0.w,a1.x,a1.y,a1.z,a1.w};
                    #pragma unroll
                    for (int e = 0; e < 8; e++) v[e] = lrelu(av[e]*ss[e] + hh[e]);
                }
            } else {
                const float* S = (cg0 < 64) ? X1 : (cg0 < 128 ? X2 : X3);
                int co = cg0 & 63;
                float4 a0 = *(const float4*)&S[(row0 + r)*64 + co + kg*8];
                float4 a1 = *(const float4*)&S[(row0 + r)*64 + co + kg*8 + 4];
                v[0]=a0.x; v[1]=a0.y; v[2]=a0.z; v[3]=a0.w;
                v[4]=a1.x; v[5]=a1.y; v[6]=a1.z; v[7]=a1.w;
            }
            union { bf16 h[8]; uint4 u; } ph, pl;
            #pragma unroll
            for (int e = 0; e < 8; e++) split2b(v[e], ph.h[e], pl.h[e]);
            *(uint4*)(smem + AH + r*64 + kg*16) = ph.u;
            *(uint4*)(smem + AL + r*64 + kg*16) = pl.u;
        }
        // ---- stage B (BN cols x 32 k) ----
        #pragma unroll
        for (int it = 0; it < BN/64; it++){
            int i = tid + it*256;
            int n = i >> 2, kg = i & 3;
            float4 b0 = *(const float4*)&w[(size_t)(col0 + n)*WST + WOFF + cg0 + kg*8];
            float4 b1 = *(const float4*)&w[(size_t)(col0 + n)*WST + WOFF + cg0 + kg*8 + 4];
            float v[8] = {b0.x,b0.y,b0.z,b0.w,b1.x,b1.y,b1.z,b1.w};
            union { bf16 h[8]; uint4 u; } ph, pl;
            #pragma unroll
            for (int e = 0; e < 8; e++) split2b(v[e], ph.h[e], pl.h[e]);
            *(uint4*)(smem + BH + n*64 + kg*16) = ph.u;
            *(uint4*)(smem + BL + n*64 + kg*16) = pl.u;
        }
        __syncthreads();
        #pragma unroll
        for (int rt2 = 0; rt2 < RT2; rt2++){
            int ar = (wv*RPW + rt2*16 + rl)*64 + g*16;
            bf16x8 ah = *(const bf16x8*)(smem + AH + ar);
            bf16x8 al = *(const bf16x8*)(smem + AL + ar);
            #pragma unroll
            for (int c2 = 0; c2 < C2; c2++){
                int br = (c2*16 + rl)*64 + g*16;
                bf16x8 bh = *(const bf16x8*)(smem + BH + br);
                bf16x8 bl = *(const bf16x8*)(smem + BL + br);
                acc[rt2][c2] = __builtin_amdgcn_mfma_f32_16x16x32_bf16(al, bh, acc[rt2][c2], 0, 0, 0);
                acc[rt2][c2] = __builtin_amdgcn_mfma_f32_16x16x32_bf16(ah, bl, acc[rt2][c2], 0, 0, 0);
                acc[rt2][c2] = __builtin_amdgcn_mfma_f32_16x16x32_bf16(ah, bh, acc[rt2][c2], 0, 0, 0);
            }
        }
    }
    // lane's element (rt2,c2,rr): row = row0 + wv*RPW + rt2*16 + g*4 + rr ; col = col0 + c2*16 + rl
    if (MODE == 3){
        #pragma unroll
        for (int c2 = 0; c2 < C2; c2++){
            float c7 = C7[b*512 + col0 + c2*16 + rl];
            #pragma unroll
            for (int rt2 = 0; rt2 < RT2; rt2++)
                #pragma unroll
                for (int rr = 0; rr < 4; rr++) acc[rt2][c2][rr] += c7;
        }
    }
    if (STMODE == 1){
        #pragma unroll
        for (int rt2 = 0; rt2 < RT2; rt2++)
            #pragma unroll
            for (int c2 = 0; c2 < C2; c2++){
                int colg = col0 + c2*16 + rl;
                int rowg = row0 + wv*RPW + rt2*16 + g*4;
                #pragma unroll
                for (int rr = 0; rr < 4; rr++)
                    HST[(size_t)(rowg + rr)*COUT + colg] = (TST)acc[rt2][c2][rr];
            }
    } else if (STMODE == 2){
        int nb = (row0 & (NN-1)) + wv*RPW + g*4;
        #pragma unroll
        for (int rt2 = 0; rt2 < RT2; rt2++)
            #pragma unroll
            for (int c2 = 0; c2 < C2; c2++){
                float* o = out1t + b*256*NN + (size_t)(col0 + c2*16 + rl)*NN + nb + rt2*16;
                *(float4*)o = make_float4(acc[rt2][c2][0], acc[rt2][c2][1], acc[rt2][c2][2], acc[rt2][c2][3]);
            }
    }
    __syncthreads();
    float* sbuf = (float*)smem;
    float* qbuf = (float*)smem + 16*BN;
    float* mbuf = (float*)smem + 32*BN;
    int gi = wv*4 + g;
    #pragma unroll
    for (int c2 = 0; c2 < C2; c2++){
        float sv = 0.f, qv = 0.f, mv = -INFINITY;
        #pragma unroll
        for (int rt2 = 0; rt2 < RT2; rt2++)
            #pragma unroll
            for (int rr = 0; rr < 4; rr++){
                float v = acc[rt2][c2][rr];
                sv += v;
                qv += v*v;
                if (MAXN) mv = fmaxf(mv, v);
            }
        sbuf[gi*BN + c2*16 + rl] = sv;
        qbuf[gi*BN + c2*16 + rl] = qv;
        if (MAXN) mbuf[gi*BN + c2*16 + rl] = mv;
    }
    __syncthreads();
    if (tid < BN){
        double t = 0.0;
        #pragma unroll
        for (int k = 0; k < 16; k++) t += (double)sbuf[k*BN + tid];
        atomicAdd(&dsum[col0 + tid], t);
        if (MAXN){
            float mm = -INFINITY;
            #pragma unroll
            for (int k = 0; k < 16; k++) mm = fmaxf(mm, mbuf[k*BN + tid]);
            part[rt*1024 + col0 + tid] = mm;
        }
    } else if (tid < 2*BN){
        int c = tid - BN;
        double t = 0.0;
        #pragma unroll
        for (int k = 0; k < 16; k++) t += (double)qbuf[k*BN + c];
        atomicAdd(&dssq[col0 + c], t);
    }
}

// ---------------- reduce partial maxes, fused L5 finalize + bn6+lrelu ----------------
__global__ void k_gmax_fin(const float* __restrict__ part,
                           const double* __restrict__ dsum, const double* __restrict__ dssq,
                           const float* __restrict__ g, const float* __restrict__ b,
                           float* __restrict__ gmax){
    __shared__ float lsc[1024];
    __shared__ float lsh[1024];
    const double invP = 1.0 / (double)(BB*NN);
    for (int c = threadIdx.x; c < 1024; c += 256){
        double sm = dsum[c], sq = dssq[c];
        double m = sm * invP;
        double v = sq * invP - m*m;
        if (v < 0.0) v = 0.0;
        float rs = (float)(1.0 / sqrt(v + 1e-5));
        float sc = g[c] * rs;
        lsc[c] = sc;
        lsh[c] = b[c] - (float)m*sc;
    }
    __syncthreads();
    int t = blockIdx.x*256 + threadIdx.x;
    int bb2 = t >> 10, c = t & 1023;
    float m = -INFINITY;
    #pragma unroll
    for (int k = 0; k < 16; k++) m = fmaxf(m, part[(bb2*16 + k)*1024 + c]);
    gmax[t] = lrelu(m*lsc[c] + lsh[c]);
}

// ---------------- tier C: BN8+lrelu + transpose from stored H8 bf16 ----------------
__global__ __launch_bounds__(256) void k_final_b(const bf16* __restrict__ H8,
                                                 const float* __restrict__ scale,
                                                 const float* __restrict__ shift,
                                                 float* __restrict__ out1){
    __shared__ float tile[64*65];
    int bi = blockIdx.x;
    int b  = bi / 128;
    int r  = bi % 128;
    int nt = r >> 2, ot = r & 3;
    for (int i = threadIdx.x; i < 64*64; i += 256){
        int o = i & 63, nl = i >> 6;
        float v = (float)H8[((b*NN) + nt*64 + nl)*256 + ot*64 + o];
        int oc = ot*64 + o;
        tile[o*65 + nl] = lrelu(v*scale[oc] + shift[oc]);
    }
    __syncthreads();
    for (int i = threadIdx.x; i < 64*64; i += 256){
        int nl = i & 63, o = i >> 6;
        out1[b*256*NN + (ot*64 + o)*NN + nt*64 + nl] = tile[o*65 + nl];
    }
}

// ---------------- host launcher ----------------
extern "C" void kernel_launch(void* const* d_in, const int* in_sizes, int n_in,
                              void* d_out, int out_size, void* d_ws, size_t ws_size,
                              hipStream_t stream){
    const float* x = (const float*)d_in[0];
    const float *w[8], *g[8], *bb[8];
    for (int i = 0; i < 8; i++){
        w[i]  = (const float*)d_in[1 + i*3];
        g[i]  = (const float*)d_in[2 + i*3];
        bb[i] = (const float*)d_in[3 + i*3];
    }
    float* ws  = (float*)d_ws;
    float* X1  = ws + OFF_X1;
    float* X2  = ws + OFF_X2;
    float* X3  = ws + OFF_X3;
    float* SQN = ws + OFF_SQN;
    float* GMAX= ws + OFF_GMAX;
    float* PART= ws + OFF_PART;
    float* C7  = ws + OFF_PART + 131072;
    double* SLOTS = (double*)(ws + OFF_PART + 135168);   // 20480 doubles (L0..L4 slot stats)
    double* DS = (double*)(ws + OFF_STATS);
    float*  FS = ws + OFF_STATS + 8448;
    int*   IDX = (int*)(ws + OFF_IDX);

    float* out0 = (float*)d_out;
    float* out1 = out0 + BB*NN*CC;
    float* P    = out1;
    float* Q    = out1 + 1048576;
    float* GRAM0= out1;
    float* GRAM1= ws + BASE_END;
    bool dualGram = ws_size >= (size_t)(BASE_END + 4194304)*4;

    const int chs[8]   = {64,64,64,64,64,1024,512,256};
    const int base[8]  = {0,128,256,384,512,640,2688,3712};
    double *SUMp[8], *SSQp[8];
    float  *SCp[8],  *SHp[8];
    for (int L = 0; L < 8; L++){
        if (L < 5){
            SUMp[L] = SLOTS + L*2*64*NSLOT;
            SSQp[L] = SLOTS + L*2*64*NSLOT + 64*NSLOT;
        } else {
            SUMp[L] = DS + base[L];
            SSQp[L] = DS + base[L] + chs[L];
        }
        SCp[L]  = FS + base[L];
        SHp[L]  = FS + base[L] + chs[L];
    }
    const double invE = 1.0 / (double)(BB*NN*KK);
    const double invP = 1.0 / (double)(BB*NN);

    hipMemsetAsync(DS, 0, 4224*sizeof(double), stream);
    hipMemsetAsync(SLOTS, 0, 5*2*64*NSLOT*sizeof(double), stream);
    k_echo<<<576,256,0,stream>>>(x, out0);

    // ---- stage 1 ----
    k_knn3<<<BB*NN/4,256,0,stream>>>(x, IDX);
    k_pq9<<<512,256,0,stream>>>(x, w[0], P, Q);
    k_hstats<false><<<4096,256,0,stream>>>(P, Q, IDX, nullptr, SUMp[0], SSQp[0]);
    k_finalize<<<1,256,0,stream>>>(SUMp[0],SSQp[0],g[0],bb[0],SCp[0],SHp[0],64,invE,NSLOT);
    k_edgegemm<<<4096,256,0,stream>>>(P, Q, IDX, SCp[0], SHp[0], w[1], X1, SUMp[1], SSQp[1]);
    k_bnact<<<1024,256,0,stream>>>(X1, SUMp[1], SSQp[1], g[1], bb[1]);

    // ---- stage 2 & 3 knn + edge ----
    for (int stage = 0; stage < 2; stage++){
        float* Xs = (stage == 0) ? X1 : X2;
        k_sqnorm<<<4096,256,0,stream>>>(Xs, SQN);
        if (dualGram){
            for (int pr = 0; pr < 4; pr++){
                k_gram2<<<512,256,0,stream>>>(Xs, GRAM0, GRAM1, pr*2);
                k_sel2<<<1024,256,0,stream>>>(GRAM0, GRAM1, SQN + pr*2*NN, IDX + pr*2*NN*KK);
            }
        } else {
            for (int b = 0; b < BB; b++){
                k_gram2<<<256,256,0,stream>>>(Xs, GRAM0, GRAM0, b);
                k_sel2<<<512,256,0,stream>>>(GRAM0, GRAM0, SQN + b*NN, IDX + b*NN*KK);
            }
        }
        if (stage == 0){
            k_pq64<<<512,256,0,stream>>>(X1, w[2], P, Q);
            k_hstats<false><<<4096,256,0,stream>>>(P, Q, IDX, nullptr, SUMp[2], SSQp[2]);
            k_finalize<<<1,256,0,stream>>>(SUMp[2],SSQp[2],g[2],bb[2],SCp[2],SHp[2],64,invE,NSLOT);
            k_edgegemm<<<4096,256,0,stream>>>(P, Q, IDX, SCp[2], SHp[2], w[3], X2, SUMp[3], SSQp[3]);
            k_bnact<<<1024,256,0,stream>>>(X2, SUMp[3], SSQp[3], g[3], bb[3]);
        } else {
            k_pq64<<<512,256,0,stream>>>(X2, w[4], P, Q);
            k_hstats<true><<<4096,256,0,stream>>>(P, Q, IDX, X3, SUMp[4], SSQp[4]);
            k_bnact<<<1024,256,0,stream>>>(X3, SUMp[4], SSQp[4], g[4], bb[4]);
        }
    }

    // ---- layer 6 + global max ----
    k_head<2,true,0,float,float><<<1024,256,0,stream>>>(
        X1,X2,X3,(const float*)nullptr,nullptr,nullptr,nullptr,w[5],
        (float*)nullptr,nullptr,PART,SUMp[5],SSQp[5]);
    k_gmax_fin<<<32,256,0,stream>>>(PART, SUMp[5], SSQp[5], g[5], bb[5], GMAX);
    k_c7<<<512,256,0,stream>>>(GMAX, w[6], C7);

    // ---- layers 7/8, tiered by ws_size ----
    if (ws_size >= (size_t)12161536*4){
        float* H7f = ws + BASE_END;
        k_head<3,false,1,float,float><<<1024,256,0,stream>>>(
            X1,X2,X3,(const float*)nullptr,C7,nullptr,nullptr,w[6],
            H7f,nullptr,nullptr,SUMp[6],SSQp[6]);
        k_finalize<<<2,256,0,stream>>>(SUMp[6],SSQp[6],g[6],bb[6],SCp[6],SHp[6],512,invP,1);
        k_head<4,false,2,float,float><<<1024,256,0,stream>>>(
            nullptr,nullptr,nullptr,H7f,nullptr,SCp[6],SHp[6],w[7],
            (float*)nullptr,out1,nullptr,SUMp[7],SSQp[7]);
        k_finalize<<<1,256,0,stream>>>(SUMp[7],SSQp[7],g[7],bb[7],SCp[7],SHp[7],256,invP,1);
        k_bnact8<<<4096,256,0,stream>>>(out1, SCp[7], SHp[7]);
    } else if (ws_size >= (size_t)7967232*4){
        bf16* H7b = (bf16*)(ws + BASE_END);
        k_head<3,false,1,bf16,float><<<1024,256,0,stream>>>(
            X1,X2,X3,(const float*)nullptr,C7,nullptr,nullptr,w[6],
            H7b,nullptr,nullptr,SUMp[6],SSQp[6]);
        k_finalize<<<2,256,0,stream>>>(SUMp[6],SSQp[6],g[6],bb[6],SCp[6],SHp[6],512,invP,1);
        k_head<4,false,2,float,bf16><<<1024,256,0,stream>>>(
            nullptr,nullptr,nullptr,H7b,nullptr,SCp[6],SHp[6],w[7],
            (float*)nullptr,out1,nullptr,SUMp[7],SSQp[7]);
        k_finalize<<<1,256,0,stream>>>(SUMp[7],SSQp[7],g[7],bb[7],SCp[7],SHp[7],256,invP,1);
        k_bnact8<<<4096,256,0,stream>>>(out1, SCp[7], SHp[7]);
    } else {
        bf16* H7b = (bf16*)out1;
        bf16* H8b = (bf16*)(ws + OFF_X1);
        k_head<3,false,1,bf16,float><<<1024,256,0,stream>>>(
            X1,X2,X3,(const float*)nullptr,C7,nullptr,nullptr,w[6],
            H7b,nullptr,nullptr,SUMp[6],SSQp[6]);
        k_finalize<<<2,256,0,stream>>>(SUMp[6],SSQp[6],g[6],bb[6],SCp[6],SHp[6],512,invP,1);
        k_head<4,false,1,bf16,bf16><<<1024,256,0,stream>>>(
            nullptr,nullptr,nullptr,H7b,nullptr,SCp[6],SHp[6],w[7],
            H8b,nullptr,nullptr,SUMp[7],SSQp[7]);
        k_finalize<<<1,256,0,stream>>>(SUMp[7],SSQp[7],g[7],bb[7],SCp[7],SHp[7],256,invP,1);
        k_final_b<<<1024,256,0,stream>>>(H8b, SCp[7], SHp[7], out1);
    }
}

// Round 15
// 684.351 us; speedup vs baseline: 1.0462x; 1.0462x over previous
//
#include <hip/hip_runtime.h>
#include <hip/hip_bf16.h>

typedef __hip_bfloat16 bf16;

#define BB 8
#define NN 2048
#define CC 9
#define KK 20
#define NSLOT 32

// ---------------- ws layout (float elements) ----------------
static constexpr int OFF_X1   = 0;               // 1048576 (16384x64 fp32)
static constexpr int OFF_X2   = 1048576;         // 1048576
static constexpr int OFF_X3   = 2097152;         // 1048576
static constexpr int OFF_SQN  = 3145728;         // 16384
static constexpr int OFF_GMAX = 3162112;         // 8192
static constexpr int OFF_PART = 3170304;         // 262144 (PART 131072 | C7 4096 | SLOTS 40960)
static constexpr int OFF_STATS= 3432448;         // 12800 (4224 doubles)
static constexpr int OFF_IDX  = 3445248;         // 327680 (int32)
static constexpr int BASE_END = 3772928;         // 15.1 MB
// SLOTS: slot-spread double stats for the 64-ch layers (L0..L4), 32x less L2-line contention.
// BASE_END region (lifetimes disjoint): GRAM1 fp32 16MB (knn stages) | H7 (layer 7+)
// r8:  LDS strides for float4 access MUST be 0 mod 4 dwords.
// r9:  triangle-gram mirror writes (lane-scattered) lose to full coalesced gram.
// r11: shrinking per-thread acc lets the compiler pipeline into VGPR=256. 128x128 gram only.
// r13/r14 A/B: a 1-2 block dispatch on the serial chain costs ~10us (launch+drain).
//      Fused per-block finalize (even with a 32KB slot re-read in 4096 blocks,
//      +6.7us/dispatch) still beats the separate dispatch by ~4us. Fuse ALL
//      finalizes into consumers; r15 removes the last two (L6 into head<4>,
//      L7 into bnact8/final_b).

typedef __attribute__((ext_vector_type(8))) short bf16x8;
typedef __attribute__((ext_vector_type(4))) float f32x4;

__device__ __forceinline__ float lrelu(float x){ return x >= 0.f ? x : 0.2f * x; }

__device__ __forceinline__ void store4(float* p, float a, float b, float c, float d){
    *(float4*)p = make_float4(a,b,c,d);
}
__device__ __forceinline__ void store4(bf16* p, float a, float b, float c, float d){
    union { bf16 h[4]; uint2 u; } pk;
    pk.h[0] = (bf16)a; pk.h[1] = (bf16)b; pk.h[2] = (bf16)c; pk.h[3] = (bf16)d;
    *(uint2*)p = pk.u;
}

// 2-way bf16 split: v = h + l to ~2^-16 relative
__device__ __forceinline__ void split2b(float v, bf16 &h, bf16 &l){
    h = (bf16)v;
    l = (bf16)(v - (float)h);
}

// float -> order-preserving uint32
__device__ __forceinline__ unsigned f2sort(float f){
    unsigned b = __float_as_uint(f);
    return b ^ (unsigned)(((int)b >> 31) | (int)0x80000000);
}

// per-block BN finalize for the 64-ch slot-spread layers (edge count): arithmetic
// identical to the old k_finalize (same double exprs, same slot order).
__device__ __forceinline__ void blk_fin64(const double* __restrict__ dsum,
                                          const double* __restrict__ dssq,
                                          const float* __restrict__ g, const float* __restrict__ b,
                                          float* lsc, float* lsh, int tid){
    const double inv_cnt = 1.0 / (double)(BB*NN*KK);
    if (tid < 64){
        int c = tid;
        double sm = 0.0, sq = 0.0;
        for (int s = 0; s < NSLOT; s++){ sm += dsum[s*64 + c]; sq += dssq[s*64 + c]; }
        double m = sm * inv_cnt;
        double v = sq * inv_cnt - m*m;
        if (v < 0.0) v = 0.0;
        float rs = (float)(1.0 / sqrt(v + 1e-5));
        float sc = g[c] * rs;
        lsc[c] = sc;
        lsh[c] = b[c] - (float)m*sc;
    }
}

// per-block BN finalize, nslot=1, per-point count (layers 5..7): identical to
// k_finalize(ch, invP, 1) arithmetic.
__device__ __forceinline__ void blk_finP(const double* __restrict__ dsum,
                                         const double* __restrict__ dssq,
                                         const float* __restrict__ g, const float* __restrict__ b,
                                         float* lsc, float* lsh, int ch, int tid){
    const double invP = 1.0 / (double)(BB*NN);
    for (int c = tid; c < ch; c += 256){
        double sm = dsum[c], sq = dssq[c];
        double m = sm * invP;
        double v = sq * invP - m*m;
        if (v < 0.0) v = 0.0;
        float rs = (float)(1.0 / sqrt(v + 1e-5));
        float sc = g[c] * rs;
        lsc[c] = sc;
        lsh[c] = b[c] - (float)m*sc;
    }
}

// exact fallback: 20x argmax-extract (desc value, asc index) — rare path
__device__ __forceinline__ void fallback_extract(unsigned (&u)[32], int lane, int* __restrict__ orow){
    for (int it = 0; it < KK; it++){
        unsigned bv = u[0]; int bj = 0;
        #pragma unroll
        for (int j = 1; j < 32; j++) if (u[j] > bv){ bv = u[j]; bj = j; }
        int bm = bj*64 + lane;
        #pragma unroll
        for (int off = 32; off >= 1; off >>= 1){
            unsigned ov = __shfl_xor(bv, off);
            int om = __shfl_xor(bm, off);
            if (ov > bv || (ov == bv && om < bm)){ bv = ov; bm = om; }
        }
        if (lane == 0) orow[it] = bm;
        if ((bm & 63) == lane) u[bm >> 6] = 0u;
    }
}

// ---------------- exact top-20 (largest) of 2048 candidates, one wave ----------------
__device__ __forceinline__ void topk20(unsigned (&u)[32], int lane,
                                       unsigned* sval, unsigned* sidx, int* __restrict__ orow){
    unsigned mx = 0u;
    #pragma unroll
    for (int j = 0; j < 32; j++) mx = (u[j] > mx) ? u[j] : mx;
    unsigned v = ~mx;
    #pragma unroll
    for (int k = 2; k <= 64; k <<= 1){
        #pragma unroll
        for (int j = k >> 1; j > 0; j >>= 1){
            unsigned o = __shfl_xor(v, j);
            bool keepMin = ((lane & k) == 0) == ((lane & j) == 0);
            bool less = (o < v);
            v = (keepMin == less) ? o : v;
        }
    }
    unsigned t0 = ~__shfl(v, 19);
    unsigned mask = 0u;
    #pragma unroll
    for (int j = 0; j < 32; j++) if (u[j] >= t0) mask |= (1u << j);
    int cnt = __popc(mask);
    int incl = cnt;
    #pragma unroll
    for (int off = 1; off < 64; off <<= 1){
        int t = __shfl_up(incl, off);
        if (lane >= off) incl += t;
    }
    int total = __shfl(incl, 63);
    if (total <= 64){
        int slot = incl - cnt;
        unsigned mm = mask;
        while (mm){
            int j = __ffs(mm) - 1;
            mm &= mm - 1u;
            sval[slot] = u[j];
            sidx[slot] = (unsigned)(j*64 + lane);
            slot++;
        }
        __threadfence_block();
        unsigned long long c = ~0ULL;
        if (lane < total)
            c = (((unsigned long long)(~sval[lane])) << 32) | (unsigned long long)sidx[lane];
        #pragma unroll
        for (int k = 2; k <= 64; k <<= 1){
            #pragma unroll
            for (int j = k >> 1; j > 0; j >>= 1){
                unsigned long long o = __shfl_xor(c, j);
                bool keepMin = ((lane & k) == 0) == ((lane & j) == 0);
                bool less = (o < c);
                c = (keepMin == less) ? o : c;
            }
        }
        if (lane < KK) orow[lane] = (int)(c & 0xffffffffULL);
    } else {
        fallback_extract(u, lane, orow);
    }
}

// ---------------- K0: echo (B,C,N) -> (B,N,C) fp32 ----------------
__global__ void k_echo(const float* __restrict__ x, float* __restrict__ out0){
    int t = blockIdx.x * 256 + threadIdx.x;
    if (t >= BB*CC*NN) return;
    int b = t / (CC*NN); int r = t % (CC*NN); int c = r / NN; int n = r % NN;
    out0[(b*NN + n)*CC + c] = x[t];
}

// ---------------- K1: knn on 3-d coords ----------------
__global__ __launch_bounds__(256) void k_knn3(const float* __restrict__ x, int* __restrict__ idx){
    __shared__ float crd[NN*3];
    __shared__ unsigned sval[4*64];
    __shared__ unsigned sidx[4*64];
    int b  = blockIdx.x / (NN/4);
    int rb = blockIdx.x % (NN/4);
    for (int c = 0; c < 3; c++)
        for (int p = threadIdx.x; p < NN; p += 256)
            crd[p*3 + c] = x[(b*CC + 6 + c)*NN + p];
    __syncthreads();
    int lane = threadIdx.x & 63;
    int wid  = threadIdx.x >> 6;
    int n = rb*4 + wid;
    float qx = crd[n*3], qy = crd[n*3+1], qz = crd[n*3+2];
    float sqn = qx*qx + qy*qy + qz*qz;
    unsigned u[32];
    #pragma unroll
    for (int j = 0; j < 32; j++){
        int m = j*64 + lane;
        float mx = crd[m*3], my = crd[m*3+1], mz = crd[m*3+2];
        float d = 2.f*(qx*mx + qy*my + qz*mz) - sqn - (mx*mx + my*my + mz*mz);
        u[j] = f2sort(d);
    }
    topk20(u, lane, sval + wid*64, sidx + wid*64, idx + (b*NN + n)*KK);
}

// ---------------- P/Q stage 1: 32-row blocks ----------------
__global__ __launch_bounds__(256) void k_pq9(const float* __restrict__ x, const float* __restrict__ w,
                                             float* __restrict__ P, float* __restrict__ Q){
    __shared__ __align__(16) float Xs[32*16];
    __shared__ __align__(16) float Wp[12*68];
    __shared__ __align__(16) float Wq[12*68];
    int row0 = blockIdx.x * 32;
    int b  = row0 >> 11;
    int n0 = row0 & (NN-1);
    int tx = threadIdx.x & 15, ty = threadIdx.x >> 4;
    for (int i = threadIdx.x; i < 32*12; i += 256){
        int r = i & 31, c = i >> 5;
        Xs[r*16 + c] = (c < 9) ? x[(b*CC + c)*NN + n0 + r] : 0.f;
    }
    for (int i = threadIdx.x; i < 64*12; i += 256){
        int c = i % 12, o = i / 12;
        float a = 0.f, dd = 0.f;
        if (c < 9){
            a  = w[o*18 + c];
            dd = w[o*18 + 9 + c] - a;
        }
        Wp[c*68 + o] = a;
        Wq[c*68 + o] = dd;
    }
    __syncthreads();
    float ap[2][4] = {{0.f}}, aq[2][4] = {{0.f}};
    for (int c0 = 0; c0 < 12; c0 += 4){
        float wp4[16], wq4[16];
        #pragma unroll
        for (int q = 0; q < 4; q++){
            *(float4*)&wp4[q*4] = *(const float4*)&Wp[(c0 + q)*68 + tx*4];
            *(float4*)&wq4[q*4] = *(const float4*)&Wq[(c0 + q)*68 + tx*4];
        }
        #pragma unroll
        for (int ii = 0; ii < 2; ii++){
            float4 x4 = *(const float4*)&Xs[(ty*2 + ii)*16 + c0];
            #pragma unroll
            for (int jj = 0; jj < 4; jj++){
                ap[ii][jj] += x4.x*wp4[jj] + x4.y*wp4[4+jj] + x4.z*wp4[8+jj] + x4.w*wp4[12+jj];
                aq[ii][jj] += x4.x*wq4[jj] + x4.y*wq4[4+jj] + x4.z*wq4[8+jj] + x4.w*wq4[12+jj];
            }
        }
    }
    #pragma unroll
    for (int ii = 0; ii < 2; ii++){
        int row = row0 + ty*2 + ii;
        store4(&P[row*64 + tx*4], ap[ii][0], ap[ii][1], ap[ii][2], ap[ii][3]);
        store4(&Q[row*64 + tx*4], aq[ii][0], aq[ii][1], aq[ii][2], aq[ii][3]);
    }
}

// ---------------- P/Q stages 2/3: 32-row blocks ----------------
__global__ __launch_bounds__(256) void k_pq64(const float* __restrict__ X, const float* __restrict__ w,
                                              float* __restrict__ P, float* __restrict__ Q){
    __shared__ __align__(16) float Xs[32*68];
    __shared__ __align__(16) float Wp[64*68];
    __shared__ __align__(16) float Wq[64*68];
    int row0 = blockIdx.x * 32;
    int tx = threadIdx.x & 15, ty = threadIdx.x >> 4;
    for (int i = threadIdx.x; i < 32*64; i += 256){
        int c = i & 63, r = i >> 6;
        Xs[r*68 + c] = X[(row0 + r)*64 + c];
    }
    for (int i = threadIdx.x; i < 64*64; i += 256){
        int c = i & 63, o = i >> 6;
        float a  = w[o*128 + c];
        Wp[c*68 + o] = a;
        Wq[c*68 + o] = w[o*128 + 64 + c] - a;
    }
    __syncthreads();
    float ap[2][4] = {{0.f}}, aq[2][4] = {{0.f}};
    for (int c0 = 0; c0 < 64; c0 += 4){
        float wp4[16], wq4[16];
        #pragma unroll
        for (int q = 0; q < 4; q++){
            *(float4*)&wp4[q*4] = *(const float4*)&Wp[(c0 + q)*68 + tx*4];
            *(float4*)&wq4[q*4] = *(const float4*)&Wq[(c0 + q)*68 + tx*4];
        }
        #pragma unroll
        for (int ii = 0; ii < 2; ii++){
            float4 x4 = *(const float4*)&Xs[(ty*2 + ii)*68 + c0];
            #pragma unroll
            for (int jj = 0; jj < 4; jj++){
                ap[ii][jj] += x4.x*wp4[jj] + x4.y*wp4[4+jj] + x4.z*wp4[8+jj] + x4.w*wp4[12+jj];
                aq[ii][jj] += x4.x*wq4[jj] + x4.y*wq4[4+jj] + x4.z*wq4[8+jj] + x4.w*wq4[12+jj];
            }
        }
    }
    #pragma unroll
    for (int ii = 0; ii < 2; ii++){
        int row = row0 + ty*2 + ii;
        store4(&P[row*64 + tx*4], ap[ii][0], ap[ii][1], ap[ii][2], ap[ii][3]);
        store4(&Q[row*64 + tx*4], aq[ii][0], aq[ii][1], aq[ii][2], aq[ii][3]);
    }
}

// ---------------- PASS A: stats of h = P[j]+Q[n]; optional fused max-over-k ----------------
template<bool DOMAX>
__global__ __launch_bounds__(256) void k_hstats(const float* __restrict__ P, const float* __restrict__ Q,
                                                const int* __restrict__ nbr, float* __restrict__ Xraw,
                                                double* __restrict__ dsum, double* __restrict__ dssq){
    __shared__ float sbuf[16*64];
    __shared__ float qbuf[16*64];
    int row0 = blockIdx.x * 80;
    int slot = blockIdx.x & (NSLOT-1);
    int tx = threadIdx.x & 15, ty = threadIdx.x >> 4;
    int ng = (row0 + ty*5) / 20;
    int b  = ng >> 11;
    float4 q4 = *(const float4*)&Q[ng*64 + tx*4];
    float s[4] = {0.f,0.f,0.f,0.f}, s2[4] = {0.f,0.f,0.f,0.f};
    float m[4] = {-INFINITY,-INFINITY,-INFINITY,-INFINITY};
    #pragma unroll
    for (int ii = 0; ii < 5; ii++){
        int e = row0 + ty*5 + ii;
        int j = nbr[e];
        float4 p4 = *(const float4*)&P[((b << 11) + j)*64 + tx*4];
        float h0 = p4.x + q4.x, h1 = p4.y + q4.y, h2 = p4.z + q4.z, h3 = p4.w + q4.w;
        s[0] += h0; s[1] += h1; s[2] += h2; s[3] += h3;
        s2[0] += h0*h0; s2[1] += h1*h1; s2[2] += h2*h2; s2[3] += h3*h3;
        if (DOMAX){
            m[0] = fmaxf(m[0], h0); m[1] = fmaxf(m[1], h1);
            m[2] = fmaxf(m[2], h2); m[3] = fmaxf(m[3], h3);
        }
    }
    #pragma unroll
    for (int jj = 0; jj < 4; jj++){
        sbuf[ty*64 + tx*4 + jj] = s[jj];
        qbuf[ty*64 + tx*4 + jj] = s2[jj];
    }
    if (DOMAX){
        #pragma unroll
        for (int off = 32; off >= 16; off >>= 1){
            #pragma unroll
            for (int jj = 0; jj < 4; jj++) m[jj] = fmaxf(m[jj], __shfl_xor(m[jj], off));
        }
        int lane = threadIdx.x & 63;
        if (lane < 16){
            int pi = ty >> 2;
            store4(&Xraw[(row0/20 + pi)*64 + tx*4], m[0], m[1], m[2], m[3]);
        }
    }
    __syncthreads();
    if (threadIdx.x < 64){
        double t = 0.0;
        #pragma unroll
        for (int k = 0; k < 16; k++) t += (double)sbuf[k*64 + threadIdx.x];
        atomicAdd(&dsum[slot*64 + threadIdx.x], t);
    } else if (threadIdx.x < 128){
        int c = threadIdx.x - 64;
        double t = 0.0;
        #pragma unroll
        for (int k = 0; k < 16; k++) t += (double)qbuf[k*64 + c];
        atomicAdd(&dssq[slot*64 + c], t);
    }
}

// ---------------- PASS B: edge GEMM, fused BN-finalize + stats + max-over-k ----------------
// r13-proven fused form: per-block sc/sh recompute (bit-identical) beats a separate
// 1-block finalize dispatch by ~4us net (r14 A/B).
__global__ __launch_bounds__(256) void k_edgegemm(const float* __restrict__ P, const float* __restrict__ Q,
                                                  const int* __restrict__ nbr,
                                                  const double* __restrict__ sum_in, const double* __restrict__ ssq_in,
                                                  const float* __restrict__ g_in, const float* __restrict__ b_in,
                                                  const float* __restrict__ w,
                                                  float* __restrict__ Xraw,
                                                  double* __restrict__ dsum, double* __restrict__ dssq){
    __shared__ __align__(16) float Fs[80*68];
    __shared__ __align__(16) float Ws[64*68];
    __shared__ __align__(16) float lsc[64];
    __shared__ __align__(16) float lsh[64];
    int row0 = blockIdx.x * 80;
    int slot = blockIdx.x & (NSLOT-1);
    int tx = threadIdx.x & 15, ty = threadIdx.x >> 4;
    blk_fin64(sum_in, ssq_in, g_in, b_in, lsc, lsh, threadIdx.x);
    __syncthreads();
    // ---- stage F: gather + bn + lrelu, float4 wide ----
    {
        int c4 = threadIdx.x & 15;
        float4 scv = *(float4*)&lsc[c4*4];
        float4 shv = *(float4*)&lsh[c4*4];
        for (int i = threadIdx.x; i < 80*16; i += 256){
            int r  = i >> 4;
            int e  = row0 + r;
            int ng = e / 20;
            int b  = ng >> 11;
            int j  = nbr[e];
            float4 p4 = *(const float4*)&P[((b << 11) + j)*64 + c4*4];
            float4 q4 = *(const float4*)&Q[ng*64 + c4*4];
            float4 f4;
            f4.x = lrelu((p4.x + q4.x)*scv.x + shv.x);
            f4.y = lrelu((p4.y + q4.y)*scv.y + shv.y);
            f4.z = lrelu((p4.z + q4.z)*scv.z + shv.z);
            f4.w = lrelu((p4.w + q4.w)*scv.w + shv.w);
            *(float4*)&Fs[r*68 + c4*4] = f4;
        }
    }
    for (int i = threadIdx.x; i < 64*16; i += 256){
        int o = i >> 4, c4 = i & 15;
        float4 w4 = *(const float4*)&w[o*64 + c4*4];
        Ws[(c4*4+0)*68 + o] = w4.x;
        Ws[(c4*4+1)*68 + o] = w4.y;
        Ws[(c4*4+2)*68 + o] = w4.z;
        Ws[(c4*4+3)*68 + o] = w4.w;
    }
    __syncthreads();
    float acc[5][4] = {{0.f}};
    for (int c0 = 0; c0 < 64; c0 += 4){
        float bb4[16];
        #pragma unroll
        for (int q = 0; q < 4; q++)
            *(float4*)&bb4[q*4] = *(const float4*)&Ws[(c0 + q)*68 + tx*4];
        #pragma unroll
        for (int ii = 0; ii < 5; ii++){
            float4 a4 = *(const float4*)&Fs[(ty*5 + ii)*68 + c0];
            #pragma unroll
            for (int jj = 0; jj < 4; jj++)
                acc[ii][jj] += a4.x*bb4[jj] + a4.y*bb4[4+jj] + a4.z*bb4[8+jj] + a4.w*bb4[12+jj];
        }
    }
    // stats into registers
    float s[4], q2[4], m[4];
    #pragma unroll
    for (int jj = 0; jj < 4; jj++){
        s[jj]  = acc[0][jj] + acc[1][jj] + acc[2][jj] + acc[3][jj] + acc[4][jj];
        q2[jj] = acc[0][jj]*acc[0][jj] + acc[1][jj]*acc[1][jj] + acc[2][jj]*acc[2][jj]
               + acc[3][jj]*acc[3][jj] + acc[4][jj]*acc[4][jj];
        m[jj]  = fmaxf(fmaxf(fmaxf(acc[0][jj], acc[1][jj]), fmaxf(acc[2][jj], acc[3][jj])), acc[4][jj]);
    }
    __syncthreads();             // all waves done reading Fs -> safe to alias
    float* sbuf = Fs;
    float* qbuf = Fs + 1024;
    #pragma unroll
    for (int jj = 0; jj < 4; jj++){
        sbuf[ty*64 + tx*4 + jj] = s[jj];
        qbuf[ty*64 + tx*4 + jj] = q2[jj];
    }
    #pragma unroll
    for (int off = 32; off >= 16; off >>= 1){
        #pragma unroll
        for (int jj = 0; jj < 4; jj++) m[jj] = fmaxf(m[jj], __shfl_xor(m[jj], off));
    }
    int lane = threadIdx.x & 63;
    if (lane < 16){
        int pi = ty >> 2;
        store4(&Xraw[(row0/20 + pi)*64 + tx*4], m[0], m[1], m[2], m[3]);
    }
    __syncthreads();
    if (threadIdx.x < 64){
        double t = 0.0;
        #pragma unroll
        for (int k = 0; k < 16; k++) t += (double)sbuf[k*64 + threadIdx.x];
        atomicAdd(&dsum[slot*64 + threadIdx.x], t);
    } else if (threadIdx.x < 128){
        int c = threadIdx.x - 64;
        double t = 0.0;
        #pragma unroll
        for (int k = 0; k < 16; k++) t += (double)qbuf[k*64 + c];
        atomicAdd(&dssq[slot*64 + c], t);
    }
}

// ---------------- in-place bn+lrelu on (16384 x 64), float4, fused finalize ----------------
__global__ void k_bnact(float* __restrict__ X,
                        const double* __restrict__ dsum, const double* __restrict__ dssq,
                        const float* __restrict__ g, const float* __restrict__ b){
    __shared__ __align__(16) float lsc[64];
    __shared__ __align__(16) float lsh[64];
    blk_fin64(dsum, dssq, g, b, lsc, lsh, threadIdx.x);
    __syncthreads();
    int t = blockIdx.x*256 + threadIdx.x;
    int e0 = t*4;
    int c0 = e0 & 63;
    float4 v = *(float4*)&X[e0];
    v.x = lrelu(v.x*lsc[c0+0] + lsh[c0+0]);
    v.y = lrelu(v.y*lsc[c0+1] + lsh[c0+1]);
    v.z = lrelu(v.z*lsc[c0+2] + lsh[c0+2]);
    v.w = lrelu(v.w*lsc[c0+3] + lsh[c0+3]);
    *(float4*)&X[e0] = v;
}

// ---------------- in-place bn8+lrelu on out1 (B,256,N), float4, fused L7 finalize ----------------
__global__ void k_bnact8(float* __restrict__ O,
                         const double* __restrict__ dsum, const double* __restrict__ dssq,
                         const float* __restrict__ g, const float* __restrict__ b){
    __shared__ __align__(16) float lsc[256];
    __shared__ __align__(16) float lsh[256];
    blk_finP(dsum, dssq, g, b, lsc, lsh, 256, threadIdx.x);
    __syncthreads();
    int t = blockIdx.x*256 + threadIdx.x;
    int e0 = t*4;
    int oc = (e0 >> 11) & 255;
    float s = lsc[oc], h = lsh[oc];
    float4 v = *(float4*)&O[e0];
    v.x = lrelu(v.x*s + h);
    v.y = lrelu(v.y*s + h);
    v.z = lrelu(v.z*s + h);
    v.w = lrelu(v.w*s + h);
    *(float4*)&O[e0] = v;
}

// ---------------- per-row squared norm ----------------
__global__ void k_sqnorm(const float* __restrict__ X, float* __restrict__ sqn){
    int row  = blockIdx.x*4 + (threadIdx.x >> 6);
    int lane = threadIdx.x & 63;
    float v = X[row*64 + lane];
    float s = v*v;
    #pragma unroll
    for (int off = 32; off >= 1; off >>= 1) s += __shfl_xor(s, off);
    if (lane == 0) sqn[row] = s;
}

// ---------------- Gram, up to 2 batches per dispatch: 128x128 tile, 8x8/thread ----------------
__global__ __launch_bounds__(256) void k_gram2(const float* __restrict__ X, float* G0, float* G1, int b0){
    __shared__ __align__(16) float As[32*132];
    __shared__ __align__(16) float Bs[32*132];
    int sub = blockIdx.x >> 8;
    int t   = blockIdx.x & 255;
    const float* Xb = X + (size_t)(b0 + sub)*NN*64;
    float* gram = sub ? G1 : G0;
    int tr = t >> 4, tc = t & 15;
    int tx = threadIdx.x & 15, ty = threadIdx.x >> 4;
    float acc[8][8];
    #pragma unroll
    for (int i = 0; i < 8; i++)
        #pragma unroll
        for (int j = 0; j < 8; j++) acc[i][j] = 0.f;
    for (int kc0 = 0; kc0 < 64; kc0 += 32){
        __syncthreads();
        for (int i = threadIdx.x; i < 128*32; i += 256){
            int k = i & 31, r = i >> 5;
            As[k*132 + r] = Xb[(tr*128 + r)*64 + kc0 + k];
            Bs[k*132 + r] = Xb[(tc*128 + r)*64 + kc0 + k];
        }
        __syncthreads();
        for (int k = 0; k < 32; k++){
            float4 a0 = *(const float4*)&As[k*132 + ty*8];
            float4 a1 = *(const float4*)&As[k*132 + ty*8 + 4];
            float4 b0v = *(const float4*)&Bs[k*132 + tx*8];
            float4 b1v = *(const float4*)&Bs[k*132 + tx*8 + 4];
            float av[8] = {a0.x,a0.y,a0.z,a0.w,a1.x,a1.y,a1.z,a1.w};
            float bv[8] = {b0v.x,b0v.y,b0v.z,b0v.w,b1v.x,b1v.y,b1v.z,b1v.w};
            #pragma unroll
            for (int i = 0; i < 8; i++)
                #pragma unroll
                for (int j = 0; j < 8; j++) acc[i][j] += av[i]*bv[j];
        }
    }
    #pragma unroll
    for (int i = 0; i < 8; i++){
        int row = tr*128 + ty*8 + i;
        *(float4*)&gram[(size_t)row*NN + tc*128 + tx*8]     = make_float4(acc[i][0],acc[i][1],acc[i][2],acc[i][3]);
        *(float4*)&gram[(size_t)row*NN + tc*128 + tx*8 + 4] = make_float4(acc[i][4],acc[i][5],acc[i][6],acc[i][7]);
    }
}

// ---------------- top-20 from gram rows, up to 2 batches per dispatch ----------------
__global__ __launch_bounds__(256) void k_sel2(const float* G0, const float* G1,
                                              const float* __restrict__ sqn, int* __restrict__ idx){
    __shared__ unsigned sval[4*64];
    __shared__ unsigned sidx[4*64];
    int sub = blockIdx.x >> 9;
    int rb  = blockIdx.x & 511;
    const float* gram = sub ? G1 : G0;
    const float* sq   = sqn + sub*NN;
    int lane = threadIdx.x & 63;
    int wid  = threadIdx.x >> 6;
    int n = rb*4 + wid;
    const float* grow = gram + (size_t)n*NN;
    float sn = sq[n];
    unsigned u[32];
    #pragma unroll
    for (int j = 0; j < 32; j++){
        int m = j*64 + lane;
        u[j] = f2sort(2.f*grow[m] - sn - sq[m]);
    }
    topk20(u, lane, sval + wid*64, sidx + wid*64, idx + (sub*NN + n)*KK);
}

// ---------------- C7 precompute ----------------
__global__ __launch_bounds__(256) void k_c7(const float* __restrict__ gmax, const float* __restrict__ w7,
                                            float* __restrict__ C7){
    __shared__ float red[4*8];
    int oc = blockIdx.x;
    int tid = threadIdx.x, lane = tid & 63, wid = tid >> 6;
    float a[8];
    #pragma unroll
    for (int b = 0; b < 8; b++) a[b] = 0.f;
    for (int k = tid; k < 1024; k += 256){
        float wv = w7[oc*1216 + k];
        #pragma unroll
        for (int b = 0; b < 8; b++) a[b] += gmax[b*1024 + k] * wv;
    }
    #pragma unroll
    for (int b = 0; b < 8; b++){
        #pragma unroll
        for (int off = 32; off >= 1; off >>= 1) a[b] += __shfl_xor(a[b], off);
        if (lane == 0) red[wid*8 + b] = a[b];
    }
    __syncthreads();
    if (tid < 8){
        float s = red[tid] + red[8 + tid] + red[16 + tid] + red[24 + tid];
        C7[tid*512 + oc] = s;
    }
}

// ---------------- unified head GEMM: per-mode tile, bf16x3 MFMA ----------------
// MODE2: 128x128   MODE3: 128x64   MODE4: 64x64  (all 1024 blocks = 4/CU)
// MODE4 fuses the L6 BN finalize (512 ch) into a per-block LDS table — removes
// the 2-block finalize dispatch (r14: small dispatches cost ~10us each).
template<int MODE, bool MAXN, int STMODE, typename TST, typename TH7>
__global__ __launch_bounds__(256) void k_head(
    const float* __restrict__ X1, const float* __restrict__ X2, const float* __restrict__ X3,
    const TH7*  __restrict__ H7, const float* __restrict__ C7,
    const double* __restrict__ f_sum, const double* __restrict__ f_ssq,
    const float* __restrict__ f_g, const float* __restrict__ f_b,
    const float* __restrict__ w,
    TST* __restrict__ HST, float* __restrict__ out1t, float* __restrict__ part,
    double* __restrict__ dsum, double* __restrict__ dssq)
{
    constexpr int CIN  = (MODE == 4) ? 512 : 192;
    constexpr int WST  = (MODE == 2) ? 192 : (MODE == 3 ? 1216 : 512);
    constexpr int WOFF = (MODE == 3) ? 1024 : 0;
    constexpr int COUT = (MODE == 2) ? 1024 : (MODE == 3 ? 512 : 256);
    constexpr int BM   = (MODE == 4) ? 64 : 128;
    constexpr int BN   = (MODE == 2) ? 128 : 64;
    constexpr int LOG2NRT = (BM == 64) ? 8 : 7;     // 16384/BM row tiles
    constexpr int RT2  = BM/64;                      // row frags per wave
    constexpr int C2   = BN/16;                      // col frags per wave
    constexpr int RPW  = BM/4;                       // rows per wave
    constexpr int FCH  = (MODE == 4) ? 512 : 1;      // fused-finalize table size
    __shared__ __align__(16) char smem[(BM+BN)*128];
    __shared__ __align__(16) float lscF[FCH];
    __shared__ __align__(16) float lshF[FCH];
    constexpr int AH = 0, AL = BM*64, BH = 2*BM*64, BL = 2*BM*64 + BN*64;
    int tid = threadIdx.x;
    int rt = blockIdx.x & ((1 << LOG2NRT) - 1);
    int ct = blockIdx.x >> LOG2NRT;
    int row0 = rt * BM;
    int col0 = ct * BN;
    int b = row0 >> 11;
    int wv = tid >> 6, l = tid & 63;
    int rl = l & 15, g = l >> 4;

    if (MODE == 4){
        blk_finP(f_sum, f_ssq, f_g, f_b, lscF, lshF, 512, tid);
        __syncthreads();
    }

    f32x4 acc[RT2][C2];
    #pragma unroll
    for (int i = 0; i < RT2; i++)
        #pragma unroll
        for (int j = 0; j < C2; j++) acc[i][j] = (f32x4){0.f,0.f,0.f,0.f};

    for (int s = 0; s < CIN/32; s++){
        int cg0 = s*32;
        __syncthreads();
        // ---- stage A (BM rows x 32 k), 8 elems/thread/iter ----
        #pragma unroll
        for (int it = 0; it < BM/64; it++){
            int i = tid + it*256;
            int r = i >> 2, kg = i & 3;
            float v[8];
            if (MODE == 4){
                float4 s0 = *(float4*)&lscF[cg0 + kg*8];
                float4 s1 = *(float4*)&lscF[cg0 + kg*8 + 4];
                float4 h0 = *(float4*)&lshF[cg0 + kg*8];
                float4 h1 = *(float4*)&lshF[cg0 + kg*8 + 4];
                float ss[8] = {s0.x,s0.y,s0.z,s0.w,s1.x,s1.y,s1.z,s1.w};
                float hh[8] = {h0.x,h0.y,h0.z,h0.w,h1.x,h1.y,h1.z,h1.w};
                if constexpr (sizeof(TH7) == 2){
                    union { uint4 q; unsigned short us[8]; } raw;
                    raw.q = *(const uint4*)&H7[(size_t)(row0 + r)*512 + cg0 + kg*8];
                    #pragma unroll
                    for (int e = 0; e < 8; e++)
                        v[e] = lrelu(__uint_as_float((unsigned)raw.us[e] << 16)*ss[e] + hh[e]);
                } else {
                    float4 a0 = *(const float4*)&H7[(size_t)(row0 + r)*512 + cg0 + kg*8];
                    float4 a1 = *(const float4*)&H7[(size_t)(row0 + r)*512 + cg0 + kg*8 + 4];
                    float av[8] = {a0.x,a0.y,a0.z,a0.w,a1.x,a1.y,a1.z,a1.w};
                    #pragma unroll
                    for (int e = 0; e < 8; e++) v[e] = lrelu(av[e]*ss[e] + hh[e]);
                }
            } else {
                const float* S = (cg0 < 64) ? X1 : (cg0 < 128 ? X2 : X3);
                int co = cg0 & 63;
                float4 a0 = *(const float4*)&S[(row0 + r)*64 + co + kg*8];
                float4 a1 = *(const float4*)&S[(row0 + r)*64 + co + kg*8 + 4];
                v[0]=a0.x; v[1]=a0.y; v[2]=a0.z; v[3]=a0.w;
                v[4]=a1.x; v[5]=a1.y; v[6]=a1.z; v[7]=a1.w;
            }
            union { bf16 h[8]; uint4 u; } ph, pl;
            #pragma unroll
            for (int e = 0; e < 8; e++) split2b(v[e], ph.h[e], pl.h[e]);
            *(uint4*)(smem + AH + r*64 + kg*16) = ph.u;
            *(uint4*)(smem + AL + r*64 + kg*16) = pl.u;
        }
        // ---- stage B (BN cols x 32 k) ----
        #pragma unroll
        for (int it = 0; it < BN/64; it++){
            int i = tid + it*256;
            int n = i >> 2, kg = i & 3;
            float4 b0 = *(const float4*)&w[(size_t)(col0 + n)*WST + WOFF + cg0 + kg*8];
            float4 b1 = *(const float4*)&w[(size_t)(col0 + n)*WST + WOFF + cg0 + kg*8 + 4];
            float v[8] = {b0.x,b0.y,b0.z,b0.w,b1.x,b1.y,b1.z,b1.w};
            union { bf16 h[8]; uint4 u; } ph, pl;
            #pragma unroll
            for (int e = 0; e < 8; e++) split2b(v[e], ph.h[e], pl.h[e]);
            *(uint4*)(smem + BH + n*64 + kg*16) = ph.u;
            *(uint4*)(smem + BL + n*64 + kg*16) = pl.u;
        }
        __syncthreads();
        #pragma unroll
        for (int rt2 = 0; rt2 < RT2; rt2++){
            int ar = (wv*RPW + rt2*16 + rl)*64 + g*16;
            bf16x8 ah = *(const bf16x8*)(smem + AH + ar);
            bf16x8 al = *(const bf16x8*)(smem + AL + ar);
            #pragma unroll
            for (int c2 = 0; c2 < C2; c2++){
                int br = (c2*16 + rl)*64 + g*16;
                bf16x8 bh = *(const bf16x8*)(smem + BH + br);
                bf16x8 bl = *(const bf16x8*)(smem + BL + br);
                acc[rt2][c2] = __builtin_amdgcn_mfma_f32_16x16x32_bf16(al, bh, acc[rt2][c2], 0, 0, 0);
                acc[rt2][c2] = __builtin_amdgcn_mfma_f32_16x16x32_bf16(ah, bl, acc[rt2][c2], 0, 0, 0);
                acc[rt2][c2] = __builtin_amdgcn_mfma_f32_16x16x32_bf16(ah, bh, acc[rt2][c2], 0, 0, 0);
            }
        }
    }
    // lane's element (rt2,c2,rr): row = row0 + wv*RPW + rt2*16 + g*4 + rr ; col = col0 + c2*16 + rl
    if (MODE == 3){
        #pragma unroll
        for (int c2 = 0; c2 < C2; c2++){
            float c7 = C7[b*512 + col0 + c2*16 + rl];
            #pragma unroll
            for (int rt2 = 0; rt2 < RT2; rt2++)
                #pragma unroll
                for (int rr = 0; rr < 4; rr++) acc[rt2][c2][rr] += c7;
        }
    }
    if (STMODE == 1){
        #pragma unroll
        for (int rt2 = 0; rt2 < RT2; rt2++)
            #pragma unroll
            for (int c2 = 0; c2 < C2; c2++){
                int colg = col0 + c2*16 + rl;
                int rowg = row0 + wv*RPW + rt2*16 + g*4;
                #pragma unroll
                for (int rr = 0; rr < 4; rr++)
                    HST[(size_t)(rowg + rr)*COUT + colg] = (TST)acc[rt2][c2][rr];
            }
    } else if (STMODE == 2){
        int nb = (row0 & (NN-1)) + wv*RPW + g*4;
        #pragma unroll
        for (int rt2 = 0; rt2 < RT2; rt2++)
            #pragma unroll
            for (int c2 = 0; c2 < C2; c2++){
                float* o = out1t + b*256*NN + (size_t)(col0 + c2*16 + rl)*NN + nb + rt2*16;
                *(float4*)o = make_float4(acc[rt2][c2][0], acc[rt2][c2][1], acc[rt2][c2][2], acc[rt2][c2][3]);
            }
    }
    __syncthreads();
    float* sbuf = (float*)smem;
    float* qbuf = (float*)smem + 16*BN;
    float* mbuf = (float*)smem + 32*BN;
    int gi = wv*4 + g;
    #pragma unroll
    for (int c2 = 0; c2 < C2; c2++){
        float sv = 0.f, qv = 0.f, mv = -INFINITY;
        #pragma unroll
        for (int rt2 = 0; rt2 < RT2; rt2++)
            #pragma unroll
            for (int rr = 0; rr < 4; rr++){
                float v = acc[rt2][c2][rr];
                sv += v;
                qv += v*v;
                if (MAXN) mv = fmaxf(mv, v);
            }
        sbuf[gi*BN + c2*16 + rl] = sv;
        qbuf[gi*BN + c2*16 + rl] = qv;
        if (MAXN) mbuf[gi*BN + c2*16 + rl] = mv;
    }
    __syncthreads();
    if (tid < BN){
        double t = 0.0;
        #pragma unroll
        for (int k = 0; k < 16; k++) t += (double)sbuf[k*BN + tid];
        atomicAdd(&dsum[col0 + tid], t);
        if (MAXN){
            float mm = -INFINITY;
            #pragma unroll
            for (int k = 0; k < 16; k++) mm = fmaxf(mm, mbuf[k*BN + tid]);
            part[rt*1024 + col0 + tid] = mm;
        }
    } else if (tid < 2*BN){
        int c = tid - BN;
        double t = 0.0;
        #pragma unroll
        for (int k = 0; k < 16; k++) t += (double)qbuf[k*BN + c];
        atomicAdd(&dssq[col0 + c], t);
    }
}

// ---------------- reduce partial maxes, fused L5 finalize + bn6+lrelu ----------------
__global__ void k_gmax_fin(const float* __restrict__ part,
                           const double* __restrict__ dsum, const double* __restrict__ dssq,
                           const float* __restrict__ g, const float* __restrict__ b,
                           float* __restrict__ gmax){
    __shared__ float lsc[1024];
    __shared__ float lsh[1024];
    blk_finP(dsum, dssq, g, b, lsc, lsh, 1024, threadIdx.x);
    __syncthreads();
    int t = blockIdx.x*256 + threadIdx.x;
    int bb2 = t >> 10, c = t & 1023;
    float m = -INFINITY;
    #pragma unroll
    for (int k = 0; k < 16; k++) m = fmaxf(m, part[(bb2*16 + k)*1024 + c]);
    gmax[t] = lrelu(m*lsc[c] + lsh[c]);
}

// ---------------- tier C: fused L7 finalize + BN8+lrelu + transpose from H8 bf16 ----------------
__global__ __launch_bounds__(256) void k_final_b(const bf16* __restrict__ H8,
                                                 const double* __restrict__ dsum, const double* __restrict__ dssq,
                                                 const float* __restrict__ g, const float* __restrict__ b,
                                                 float* __restrict__ out1){
    __shared__ float tile[64*65];
    __shared__ float lsc[256];
    __shared__ float lsh[256];
    blk_finP(dsum, dssq, g, b, lsc, lsh, 256, threadIdx.x);
    __syncthreads();
    int bi = blockIdx.x;
    int bb2 = bi / 128;
    int r  = bi % 128;
    int nt = r >> 2, ot = r & 3;
    for (int i = threadIdx.x; i < 64*64; i += 256){
        int o = i & 63, nl = i >> 6;
        float v = (float)H8[((bb2*NN) + nt*64 + nl)*256 + ot*64 + o];
        int oc = ot*64 + o;
        tile[o*65 + nl] = lrelu(v*lsc[oc] + lsh[oc]);
    }
    __syncthreads();
    for (int i = threadIdx.x; i < 64*64; i += 256){
        int nl = i & 63, o = i >> 6;
        out1[bb2*256*NN + (ot*64 + o)*NN + nt*64 + nl] = tile[o*65 + nl];
    }
}

// ---------------- host launcher ----------------
extern "C" void kernel_launch(void* const* d_in, const int* in_sizes, int n_in,
                              void* d_out, int out_size, void* d_ws, size_t ws_size,
                              hipStream_t stream){
    const float* x = (const float*)d_in[0];
    const float *w[8], *g[8], *bb[8];
    for (int i = 0; i < 8; i++){
        w[i]  = (const float*)d_in[1 + i*3];
        g[i]  = (const float*)d_in[2 + i*3];
        bb[i] = (const float*)d_in[3 + i*3];
    }
    float* ws  = (float*)d_ws;
    float* X1  = ws + OFF_X1;
    float* X2  = ws + OFF_X2;
    float* X3  = ws + OFF_X3;
    float* SQN = ws + OFF_SQN;
    float* GMAX= ws + OFF_GMAX;
    float* PART= ws + OFF_PART;
    float* C7  = ws + OFF_PART + 131072;
    double* SLOTS = (double*)(ws + OFF_PART + 135168);   // 20480 doubles (L0..L4 slot stats)
    double* DS = (double*)(ws + OFF_STATS);
    int*   IDX = (int*)(ws + OFF_IDX);

    float* out0 = (float*)d_out;
    float* out1 = out0 + BB*NN*CC;
    float* P    = out1;
    float* Q    = out1 + 1048576;
    float* GRAM0= out1;
    float* GRAM1= ws + BASE_END;
    bool dualGram = ws_size >= (size_t)(BASE_END + 4194304)*4;

    const int chs[8]   = {64,64,64,64,64,1024,512,256};
    const int base[8]  = {0,128,256,384,512,640,2688,3712};
    double *SUMp[8], *SSQp[8];
    for (int L = 0; L < 8; L++){
        if (L < 5){
            SUMp[L] = SLOTS + L*2*64*NSLOT;
            SSQp[L] = SLOTS + L*2*64*NSLOT + 64*NSLOT;
        } else {
            SUMp[L] = DS + base[L];
            SSQp[L] = DS + base[L] + chs[L];
        }
    }

    hipMemsetAsync(DS, 0, 4224*sizeof(double), stream);
    hipMemsetAsync(SLOTS, 0, 5*2*64*NSLOT*sizeof(double), stream);
    k_echo<<<576,256,0,stream>>>(x, out0);

    // ---- stage 1 ----
    k_knn3<<<BB*NN/4,256,0,stream>>>(x, IDX);
    k_pq9<<<512,256,0,stream>>>(x, w[0], P, Q);
    k_hstats<false><<<4096,256,0,stream>>>(P, Q, IDX, nullptr, SUMp[0], SSQp[0]);
    k_edgegemm<<<4096,256,0,stream>>>(P, Q, IDX, SUMp[0], SSQp[0], g[0], bb[0], w[1], X1, SUMp[1], SSQp[1]);
    k_bnact<<<1024,256,0,stream>>>(X1, SUMp[1], SSQp[1], g[1], bb[1]);

    // ---- stage 2 & 3 knn + edge ----
    for (int stage = 0; stage < 2; stage++){
        float* Xs = (stage == 0) ? X1 : X2;
        k_sqnorm<<<4096,256,0,stream>>>(Xs, SQN);
        if (dualGram){
            for (int pr = 0; pr < 4; pr++){
                k_gram2<<<512,256,0,stream>>>(Xs, GRAM0, GRAM1, pr*2);
                k_sel2<<<1024,256,0,stream>>>(GRAM0, GRAM1, SQN + pr*2*NN, IDX + pr*2*NN*KK);
            }
        } else {
            for (int b = 0; b < BB; b++){
                k_gram2<<<256,256,0,stream>>>(Xs, GRAM0, GRAM0, b);
                k_sel2<<<512,256,0,stream>>>(GRAM0, GRAM0, SQN + b*NN, IDX + b*NN*KK);
            }
        }
        if (stage == 0){
            k_pq64<<<512,256,0,stream>>>(X1, w[2], P, Q);
            k_hstats<false><<<4096,256,0,stream>>>(P, Q, IDX, nullptr, SUMp[2], SSQp[2]);
            k_edgegemm<<<4096,256,0,stream>>>(P, Q, IDX, SUMp[2], SSQp[2], g[2], bb[2], w[3], X2, SUMp[3], SSQp[3]);
            k_bnact<<<1024,256,0,stream>>>(X2, SUMp[3], SSQp[3], g[3], bb[3]);
        } else {
            k_pq64<<<512,256,0,stream>>>(X2, w[4], P, Q);
            k_hstats<true><<<4096,256,0,stream>>>(P, Q, IDX, X3, SUMp[4], SSQp[4]);
            k_bnact<<<1024,256,0,stream>>>(X3, SUMp[4], SSQp[4], g[4], bb[4]);
        }
    }

    // ---- layer 6 + global max ----
    k_head<2,true,0,float,float><<<1024,256,0,stream>>>(
        X1,X2,X3,(const float*)nullptr,nullptr,nullptr,nullptr,nullptr,nullptr,w[5],
        (float*)nullptr,nullptr,PART,SUMp[5],SSQp[5]);
    k_gmax_fin<<<32,256,0,stream>>>(PART, SUMp[5], SSQp[5], g[5], bb[5], GMAX);
    k_c7<<<512,256,0,stream>>>(GMAX, w[6], C7);

    // ---- layers 7/8, tiered by ws_size ----
    if (ws_size >= (size_t)12161536*4){
        float* H7f = ws + BASE_END;
        k_head<3,false,1,float,float><<<1024,256,0,stream>>>(
            X1,X2,X3,(const float*)nullptr,C7,nullptr,nullptr,nullptr,nullptr,w[6],
            H7f,nullptr,nullptr,SUMp[6],SSQp[6]);
        k_head<4,false,2,float,float><<<1024,256,0,stream>>>(
            nullptr,nullptr,nullptr,H7f,nullptr,SUMp[6],SSQp[6],g[6],bb[6],w[7],
            (float*)nullptr,out1,nullptr,SUMp[7],SSQp[7]);
        k_bnact8<<<4096,256,0,stream>>>(out1, SUMp[7], SSQp[7], g[7], bb[7]);
    } else if (ws_size >= (size_t)7967232*4){
        bf16* H7b = (bf16*)(ws + BASE_END);
        k_head<3,false,1,bf16,float><<<1024,256,0,stream>>>(
            X1,X2,X3,(const float*)nullptr,C7,nullptr,nullptr,nullptr,nullptr,w[6],
            H7b,nullptr,nullptr,SUMp[6],SSQp[6]);
        k_head<4,false,2,float,bf16><<<1024,256,0,stream>>>(
            nullptr,nullptr,nullptr,H7b,nullptr,SUMp[6],SSQp[6],g[6],bb[6],w[7],
            (float*)nullptr,out1,nullptr,SUMp[7],SSQp[7]);
        k_bnact8<<<4096,256,0,stream>>>(out1, SUMp[7], SSQp[7], g[7], bb[7]);
    } else {
        bf16* H7b = (bf16*)out1;
        bf16* H8b = (bf16*)(ws + OFF_X1);
        k_head<3,false,1,bf16,float><<<1024,256,0,stream>>>(
            X1,X2,X3,(const float*)nullptr,C7,nullptr,nullptr,nullptr,nullptr,w[6],
            H7b,nullptr,nullptr,SUMp[6],SSQp[6]);
        k_head<4,false,1,bf16,bf16><<<1024,256,0,stream>>>(
            nullptr,nullptr,nullptr,H7b,nullptr,SUMp[6],SSQp[6],g[6],bb[6],w[7],
            H8b,nullptr,nullptr,SUMp[7],SSQp[7]);
        k_final_b<<<1024,256,0,stream>>>(H8b, SUMp[7], SSQp[7], g[7], bb[7], out1);
    }
}

// Round 16
// 670.859 us; speedup vs baseline: 1.0673x; 1.0201x over previous
//
#include <hip/hip_runtime.h>
#include <hip/hip_bf16.h>

typedef __hip_bfloat16 bf16;

#define BB 8
#define NN 2048
#define CC 9
#define KK 20
#define NSLOT 32

// ---------------- ws layout (float elements) ----------------
static constexpr int OFF_X1   = 0;               // 1048576 (16384x64 fp32)
static constexpr int OFF_X2   = 1048576;         // 1048576
static constexpr int OFF_X3   = 2097152;         // 1048576
static constexpr int OFF_SQN  = 3145728;         // 16384
static constexpr int OFF_GMAX = 3162112;         // 8192
static constexpr int OFF_PART = 3170304;         // 262144: PART 131072 | C7 4096 | SLOTS 40960 | DS 8448
static constexpr int OFF_IDX  = 3445248;         // 327680 (int32)
static constexpr int BASE_END = 3772928;         // 15.1 MB
// SLOTS at OFF_PART+135168 (L0..L4 slot stats, 20480 doubles); DS directly after
// (4224 doubles) so ONE memset clears both (r16: every serial launch ~3-10us).
// r8:  LDS strides for float4 access MUST be 0 mod 4 dwords.
// r9:  triangle-gram mirror writes (lane-scattered) lose to full coalesced gram.
// r11: shrinking per-thread acc lets the compiler pipeline into VGPR=256. 128x128 gram only.
// r13/r14/r15: fuse ALL BN finalizes into consumers (per-block recompute, bit-identical);
//      a 1-2 block serial dispatch costs ~10us.
// r16: echo folded into pq9; sqnorm folded into bnact with tree-exact butterfly
//      replication (per-thread float4 squares + xor 8/4/2/1 + (x+z)+(y+w) ==
//      the 64-lane tree) -> bit-identical sqn; one memset.

typedef __attribute__((ext_vector_type(8))) short bf16x8;
typedef __attribute__((ext_vector_type(4))) float f32x4;

__device__ __forceinline__ float lrelu(float x){ return x >= 0.f ? x : 0.2f * x; }

__device__ __forceinline__ void store4(float* p, float a, float b, float c, float d){
    *(float4*)p = make_float4(a,b,c,d);
}
__device__ __forceinline__ void store4(bf16* p, float a, float b, float c, float d){
    union { bf16 h[4]; uint2 u; } pk;
    pk.h[0] = (bf16)a; pk.h[1] = (bf16)b; pk.h[2] = (bf16)c; pk.h[3] = (bf16)d;
    *(uint2*)p = pk.u;
}

// 2-way bf16 split: v = h + l to ~2^-16 relative
__device__ __forceinline__ void split2b(float v, bf16 &h, bf16 &l){
    h = (bf16)v;
    l = (bf16)(v - (float)h);
}

// float -> order-preserving uint32
__device__ __forceinline__ unsigned f2sort(float f){
    unsigned b = __float_as_uint(f);
    return b ^ (unsigned)(((int)b >> 31) | (int)0x80000000);
}

// per-block BN finalize for the 64-ch slot-spread layers (edge count): arithmetic
// identical to the old k_finalize (same double exprs, same slot order).
__device__ __forceinline__ void blk_fin64(const double* __restrict__ dsum,
                                          const double* __restrict__ dssq,
                                          const float* __restrict__ g, const float* __restrict__ b,
                                          float* lsc, float* lsh, int tid){
    const double inv_cnt = 1.0 / (double)(BB*NN*KK);
    if (tid < 64){
        int c = tid;
        double sm = 0.0, sq = 0.0;
        for (int s = 0; s < NSLOT; s++){ sm += dsum[s*64 + c]; sq += dssq[s*64 + c]; }
        double m = sm * inv_cnt;
        double v = sq * inv_cnt - m*m;
        if (v < 0.0) v = 0.0;
        float rs = (float)(1.0 / sqrt(v + 1e-5));
        float sc = g[c] * rs;
        lsc[c] = sc;
        lsh[c] = b[c] - (float)m*sc;
    }
}

// per-block BN finalize, nslot=1, per-point count (layers 5..7)
__device__ __forceinline__ void blk_finP(const double* __restrict__ dsum,
                                         const double* __restrict__ dssq,
                                         const float* __restrict__ g, const float* __restrict__ b,
                                         float* lsc, float* lsh, int ch, int tid){
    const double invP = 1.0 / (double)(BB*NN);
    for (int c = tid; c < ch; c += 256){
        double sm = dsum[c], sq = dssq[c];
        double m = sm * invP;
        double v = sq * invP - m*m;
        if (v < 0.0) v = 0.0;
        float rs = (float)(1.0 / sqrt(v + 1e-5));
        float sc = g[c] * rs;
        lsc[c] = sc;
        lsh[c] = b[c] - (float)m*sc;
    }
}

// exact fallback: 20x argmax-extract (desc value, asc index) — rare path
__device__ __forceinline__ void fallback_extract(unsigned (&u)[32], int lane, int* __restrict__ orow){
    for (int it = 0; it < KK; it++){
        unsigned bv = u[0]; int bj = 0;
        #pragma unroll
        for (int j = 1; j < 32; j++) if (u[j] > bv){ bv = u[j]; bj = j; }
        int bm = bj*64 + lane;
        #pragma unroll
        for (int off = 32; off >= 1; off >>= 1){
            unsigned ov = __shfl_xor(bv, off);
            int om = __shfl_xor(bm, off);
            if (ov > bv || (ov == bv && om < bm)){ bv = ov; bm = om; }
        }
        if (lane == 0) orow[it] = bm;
        if ((bm & 63) == lane) u[bm >> 6] = 0u;
    }
}

// ---------------- exact top-20 (largest) of 2048 candidates, one wave ----------------
__device__ __forceinline__ void topk20(unsigned (&u)[32], int lane,
                                       unsigned* sval, unsigned* sidx, int* __restrict__ orow){
    unsigned mx = 0u;
    #pragma unroll
    for (int j = 0; j < 32; j++) mx = (u[j] > mx) ? u[j] : mx;
    unsigned v = ~mx;
    #pragma unroll
    for (int k = 2; k <= 64; k <<= 1){
        #pragma unroll
        for (int j = k >> 1; j > 0; j >>= 1){
            unsigned o = __shfl_xor(v, j);
            bool keepMin = ((lane & k) == 0) == ((lane & j) == 0);
            bool less = (o < v);
            v = (keepMin == less) ? o : v;
        }
    }
    unsigned t0 = ~__shfl(v, 19);
    unsigned mask = 0u;
    #pragma unroll
    for (int j = 0; j < 32; j++) if (u[j] >= t0) mask |= (1u << j);
    int cnt = __popc(mask);
    int incl = cnt;
    #pragma unroll
    for (int off = 1; off < 64; off <<= 1){
        int t = __shfl_up(incl, off);
        if (lane >= off) incl += t;
    }
    int total = __shfl(incl, 63);
    if (total <= 64){
        int slot = incl - cnt;
        unsigned mm = mask;
        while (mm){
            int j = __ffs(mm) - 1;
            mm &= mm - 1u;
            sval[slot] = u[j];
            sidx[slot] = (unsigned)(j*64 + lane);
            slot++;
        }
        __threadfence_block();
        unsigned long long c = ~0ULL;
        if (lane < total)
            c = (((unsigned long long)(~sval[lane])) << 32) | (unsigned long long)sidx[lane];
        #pragma unroll
        for (int k = 2; k <= 64; k <<= 1){
            #pragma unroll
            for (int j = k >> 1; j > 0; j >>= 1){
                unsigned long long o = __shfl_xor(c, j);
                bool keepMin = ((lane & k) == 0) == ((lane & j) == 0);
                bool less = (o < c);
                c = (keepMin == less) ? o : c;
            }
        }
        if (lane < KK) orow[lane] = (int)(c & 0xffffffffULL);
    } else {
        fallback_extract(u, lane, orow);
    }
}

// ---------------- K1: knn on 3-d coords ----------------
__global__ __launch_bounds__(256) void k_knn3(const float* __restrict__ x, int* __restrict__ idx){
    __shared__ float crd[NN*3];
    __shared__ unsigned sval[4*64];
    __shared__ unsigned sidx[4*64];
    int b  = blockIdx.x / (NN/4);
    int rb = blockIdx.x % (NN/4);
    for (int c = 0; c < 3; c++)
        for (int p = threadIdx.x; p < NN; p += 256)
            crd[p*3 + c] = x[(b*CC + 6 + c)*NN + p];
    __syncthreads();
    int lane = threadIdx.x & 63;
    int wid  = threadIdx.x >> 6;
    int n = rb*4 + wid;
    float qx = crd[n*3], qy = crd[n*3+1], qz = crd[n*3+2];
    float sqn = qx*qx + qy*qy + qz*qz;
    unsigned u[32];
    #pragma unroll
    for (int j = 0; j < 32; j++){
        int m = j*64 + lane;
        float mx = crd[m*3], my = crd[m*3+1], mz = crd[m*3+2];
        float d = 2.f*(qx*mx + qy*my + qz*mz) - sqn - (mx*mx + my*my + mz*mz);
        u[j] = f2sort(d);
    }
    topk20(u, lane, sval + wid*64, sidx + wid*64, idx + (b*NN + n)*KK);
}

// ---------------- P/Q stage 1: 32-row blocks, fused out0 echo ----------------
__global__ __launch_bounds__(256) void k_pq9(const float* __restrict__ x, const float* __restrict__ w,
                                             float* __restrict__ P, float* __restrict__ Q,
                                             float* __restrict__ out0){
    __shared__ __align__(16) float Xs[32*16];
    __shared__ __align__(16) float Wp[12*68];
    __shared__ __align__(16) float Wq[12*68];
    int row0 = blockIdx.x * 32;
    int b  = row0 >> 11;
    int n0 = row0 & (NN-1);
    int tx = threadIdx.x & 15, ty = threadIdx.x >> 4;
    for (int i = threadIdx.x; i < 32*12; i += 256){
        int r = i & 31, c = i >> 5;
        Xs[r*16 + c] = (c < 9) ? x[(b*CC + c)*NN + n0 + r] : 0.f;
    }
    for (int i = threadIdx.x; i < 64*12; i += 256){
        int c = i % 12, o = i / 12;
        float a = 0.f, dd = 0.f;
        if (c < 9){
            a  = w[o*18 + c];
            dd = w[o*18 + 9 + c] - a;
        }
        Wp[c*68 + o] = a;
        Wq[c*68 + o] = dd;
    }
    __syncthreads();
    // fused echo: out0[(b*NN + n0+r)*9 + c] = x value (coalesced in i = r*9+c)
    for (int i = threadIdx.x; i < 32*9; i += 256){
        int r = i / 9, c = i % 9;
        out0[((size_t)(b*NN) + n0 + r)*CC + c] = Xs[r*16 + c];
    }
    float ap[2][4] = {{0.f}}, aq[2][4] = {{0.f}};
    for (int c0 = 0; c0 < 12; c0 += 4){
        float wp4[16], wq4[16];
        #pragma unroll
        for (int q = 0; q < 4; q++){
            *(float4*)&wp4[q*4] = *(const float4*)&Wp[(c0 + q)*68 + tx*4];
            *(float4*)&wq4[q*4] = *(const float4*)&Wq[(c0 + q)*68 + tx*4];
        }
        #pragma unroll
        for (int ii = 0; ii < 2; ii++){
            float4 x4 = *(const float4*)&Xs[(ty*2 + ii)*16 + c0];
            #pragma unroll
            for (int jj = 0; jj < 4; jj++){
                ap[ii][jj] += x4.x*wp4[jj] + x4.y*wp4[4+jj] + x4.z*wp4[8+jj] + x4.w*wp4[12+jj];
                aq[ii][jj] += x4.x*wq4[jj] + x4.y*wq4[4+jj] + x4.z*wq4[8+jj] + x4.w*wq4[12+jj];
            }
        }
    }
    #pragma unroll
    for (int ii = 0; ii < 2; ii++){
        int row = row0 + ty*2 + ii;
        store4(&P[row*64 + tx*4], ap[ii][0], ap[ii][1], ap[ii][2], ap[ii][3]);
        store4(&Q[row*64 + tx*4], aq[ii][0], aq[ii][1], aq[ii][2], aq[ii][3]);
    }
}

// ---------------- P/Q stages 2/3: 32-row blocks ----------------
__global__ __launch_bounds__(256) void k_pq64(const float* __restrict__ X, const float* __restrict__ w,
                                              float* __restrict__ P, float* __restrict__ Q){
    __shared__ __align__(16) float Xs[32*68];
    __shared__ __align__(16) float Wp[64*68];
    __shared__ __align__(16) float Wq[64*68];
    int row0 = blockIdx.x * 32;
    int tx = threadIdx.x & 15, ty = threadIdx.x >> 4;
    for (int i = threadIdx.x; i < 32*64; i += 256){
        int c = i & 63, r = i >> 6;
        Xs[r*68 + c] = X[(row0 + r)*64 + c];
    }
    for (int i = threadIdx.x; i < 64*64; i += 256){
        int c = i & 63, o = i >> 6;
        float a  = w[o*128 + c];
        Wp[c*68 + o] = a;
        Wq[c*68 + o] = w[o*128 + 64 + c] - a;
    }
    __syncthreads();
    float ap[2][4] = {{0.f}}, aq[2][4] = {{0.f}};
    for (int c0 = 0; c0 < 64; c0 += 4){
        float wp4[16], wq4[16];
        #pragma unroll
        for (int q = 0; q < 4; q++){
            *(float4*)&wp4[q*4] = *(const float4*)&Wp[(c0 + q)*68 + tx*4];
            *(float4*)&wq4[q*4] = *(const float4*)&Wq[(c0 + q)*68 + tx*4];
        }
        #pragma unroll
        for (int ii = 0; ii < 2; ii++){
            float4 x4 = *(const float4*)&Xs[(ty*2 + ii)*68 + c0];
            #pragma unroll
            for (int jj = 0; jj < 4; jj++){
                ap[ii][jj] += x4.x*wp4[jj] + x4.y*wp4[4+jj] + x4.z*wp4[8+jj] + x4.w*wp4[12+jj];
                aq[ii][jj] += x4.x*wq4[jj] + x4.y*wq4[4+jj] + x4.z*wq4[8+jj] + x4.w*wq4[12+jj];
            }
        }
    }
    #pragma unroll
    for (int ii = 0; ii < 2; ii++){
        int row = row0 + ty*2 + ii;
        store4(&P[row*64 + tx*4], ap[ii][0], ap[ii][1], ap[ii][2], ap[ii][3]);
        store4(&Q[row*64 + tx*4], aq[ii][0], aq[ii][1], aq[ii][2], aq[ii][3]);
    }
}

// ---------------- PASS A: stats of h = P[j]+Q[n]; optional fused max-over-k ----------------
template<bool DOMAX>
__global__ __launch_bounds__(256) void k_hstats(const float* __restrict__ P, const float* __restrict__ Q,
                                                const int* __restrict__ nbr, float* __restrict__ Xraw,
                                                double* __restrict__ dsum, double* __restrict__ dssq){
    __shared__ float sbuf[16*64];
    __shared__ float qbuf[16*64];
    int row0 = blockIdx.x * 80;
    int slot = blockIdx.x & (NSLOT-1);
    int tx = threadIdx.x & 15, ty = threadIdx.x >> 4;
    int ng = (row0 + ty*5) / 20;
    int b  = ng >> 11;
    float4 q4 = *(const float4*)&Q[ng*64 + tx*4];
    float s[4] = {0.f,0.f,0.f,0.f}, s2[4] = {0.f,0.f,0.f,0.f};
    float m[4] = {-INFINITY,-INFINITY,-INFINITY,-INFINITY};
    #pragma unroll
    for (int ii = 0; ii < 5; ii++){
        int e = row0 + ty*5 + ii;
        int j = nbr[e];
        float4 p4 = *(const float4*)&P[((b << 11) + j)*64 + tx*4];
        float h0 = p4.x + q4.x, h1 = p4.y + q4.y, h2 = p4.z + q4.z, h3 = p4.w + q4.w;
        s[0] += h0; s[1] += h1; s[2] += h2; s[3] += h3;
        s2[0] += h0*h0; s2[1] += h1*h1; s2[2] += h2*h2; s2[3] += h3*h3;
        if (DOMAX){
            m[0] = fmaxf(m[0], h0); m[1] = fmaxf(m[1], h1);
            m[2] = fmaxf(m[2], h2); m[3] = fmaxf(m[3], h3);
        }
    }
    #pragma unroll
    for (int jj = 0; jj < 4; jj++){
        sbuf[ty*64 + tx*4 + jj] = s[jj];
        qbuf[ty*64 + tx*4 + jj] = s2[jj];
    }
    if (DOMAX){
        #pragma unroll
        for (int off = 32; off >= 16; off >>= 1){
            #pragma unroll
            for (int jj = 0; jj < 4; jj++) m[jj] = fmaxf(m[jj], __shfl_xor(m[jj], off));
        }
        int lane = threadIdx.x & 63;
        if (lane < 16){
            int pi = ty >> 2;
            store4(&Xraw[(row0/20 + pi)*64 + tx*4], m[0], m[1], m[2], m[3]);
        }
    }
    __syncthreads();
    if (threadIdx.x < 64){
        double t = 0.0;
        #pragma unroll
        for (int k = 0; k < 16; k++) t += (double)sbuf[k*64 + threadIdx.x];
        atomicAdd(&dsum[slot*64 + threadIdx.x], t);
    } else if (threadIdx.x < 128){
        int c = threadIdx.x - 64;
        double t = 0.0;
        #pragma unroll
        for (int k = 0; k < 16; k++) t += (double)qbuf[k*64 + c];
        atomicAdd(&dssq[slot*64 + c], t);
    }
}

// ---------------- PASS B: edge GEMM, fused BN-finalize + stats + max-over-k ----------------
__global__ __launch_bounds__(256) void k_edgegemm(const float* __restrict__ P, const float* __restrict__ Q,
                                                  const int* __restrict__ nbr,
                                                  const double* __restrict__ sum_in, const double* __restrict__ ssq_in,
                                                  const float* __restrict__ g_in, const float* __restrict__ b_in,
                                                  const float* __restrict__ w,
                                                  float* __restrict__ Xraw,
                                                  double* __restrict__ dsum, double* __restrict__ dssq){
    __shared__ __align__(16) float Fs[80*68];
    __shared__ __align__(16) float Ws[64*68];
    __shared__ __align__(16) float lsc[64];
    __shared__ __align__(16) float lsh[64];
    int row0 = blockIdx.x * 80;
    int slot = blockIdx.x & (NSLOT-1);
    int tx = threadIdx.x & 15, ty = threadIdx.x >> 4;
    blk_fin64(sum_in, ssq_in, g_in, b_in, lsc, lsh, threadIdx.x);
    __syncthreads();
    // ---- stage F: gather + bn + lrelu, float4 wide ----
    {
        int c4 = threadIdx.x & 15;
        float4 scv = *(float4*)&lsc[c4*4];
        float4 shv = *(float4*)&lsh[c4*4];
        for (int i = threadIdx.x; i < 80*16; i += 256){
            int r  = i >> 4;
            int e  = row0 + r;
            int ng = e / 20;
            int b  = ng >> 11;
            int j  = nbr[e];
            float4 p4 = *(const float4*)&P[((b << 11) + j)*64 + c4*4];
            float4 q4 = *(const float4*)&Q[ng*64 + c4*4];
            float4 f4;
            f4.x = lrelu((p4.x + q4.x)*scv.x + shv.x);
            f4.y = lrelu((p4.y + q4.y)*scv.y + shv.y);
            f4.z = lrelu((p4.z + q4.z)*scv.z + shv.z);
            f4.w = lrelu((p4.w + q4.w)*scv.w + shv.w);
            *(float4*)&Fs[r*68 + c4*4] = f4;
        }
    }
    for (int i = threadIdx.x; i < 64*16; i += 256){
        int o = i >> 4, c4 = i & 15;
        float4 w4 = *(const float4*)&w[o*64 + c4*4];
        Ws[(c4*4+0)*68 + o] = w4.x;
        Ws[(c4*4+1)*68 + o] = w4.y;
        Ws[(c4*4+2)*68 + o] = w4.z;
        Ws[(c4*4+3)*68 + o] = w4.w;
    }
    __syncthreads();
    float acc[5][4] = {{0.f}};
    for (int c0 = 0; c0 < 64; c0 += 4){
        float bb4[16];
        #pragma unroll
        for (int q = 0; q < 4; q++)
            *(float4*)&bb4[q*4] = *(const float4*)&Ws[(c0 + q)*68 + tx*4];
        #pragma unroll
        for (int ii = 0; ii < 5; ii++){
            float4 a4 = *(const float4*)&Fs[(ty*5 + ii)*68 + c0];
            #pragma unroll
            for (int jj = 0; jj < 4; jj++)
                acc[ii][jj] += a4.x*bb4[jj] + a4.y*bb4[4+jj] + a4.z*bb4[8+jj] + a4.w*bb4[12+jj];
        }
    }
    // stats into registers
    float s[4], q2[4], m[4];
    #pragma unroll
    for (int jj = 0; jj < 4; jj++){
        s[jj]  = acc[0][jj] + acc[1][jj] + acc[2][jj] + acc[3][jj] + acc[4][jj];
        q2[jj] = acc[0][jj]*acc[0][jj] + acc[1][jj]*acc[1][jj] + acc[2][jj]*acc[2][jj]
               + acc[3][jj]*acc[3][jj] + acc[4][jj]*acc[4][jj];
        m[jj]  = fmaxf(fmaxf(fmaxf(acc[0][jj], acc[1][jj]), fmaxf(acc[2][jj], acc[3][jj])), acc[4][jj]);
    }
    __syncthreads();             // all waves done reading Fs -> safe to alias
    float* sbuf = Fs;
    float* qbuf = Fs + 1024;
    #pragma unroll
    for (int jj = 0; jj < 4; jj++){
        sbuf[ty*64 + tx*4 + jj] = s[jj];
        qbuf[ty*64 + tx*4 + jj] = q2[jj];
    }
    #pragma unroll
    for (int off = 32; off >= 16; off >>= 1){
        #pragma unroll
        for (int jj = 0; jj < 4; jj++) m[jj] = fmaxf(m[jj], __shfl_xor(m[jj], off));
    }
    int lane = threadIdx.x & 63;
    if (lane < 16){
        int pi = ty >> 2;
        store4(&Xraw[(row0/20 + pi)*64 + tx*4], m[0], m[1], m[2], m[3]);
    }
    __syncthreads();
    if (threadIdx.x < 64){
        double t = 0.0;
        #pragma unroll
        for (int k = 0; k < 16; k++) t += (double)sbuf[k*64 + threadIdx.x];
        atomicAdd(&dsum[slot*64 + threadIdx.x], t);
    } else if (threadIdx.x < 128){
        int c = threadIdx.x - 64;
        double t = 0.0;
        #pragma unroll
        for (int k = 0; k < 16; k++) t += (double)qbuf[k*64 + c];
        atomicAdd(&dssq[slot*64 + c], t);
    }
}

// ---------------- in-place bn+lrelu on (16384 x 64), float4, fused finalize ----------------
// Optionally (sqn != nullptr) also computes per-row squared norms with a
// tree-exact replication of the old 64-lane butterfly (bit-identical).
__global__ void k_bnact(float* __restrict__ X,
                        const double* __restrict__ dsum, const double* __restrict__ dssq,
                        const float* __restrict__ g, const float* __restrict__ b,
                        float* __restrict__ sqn){
    __shared__ __align__(16) float lsc[64];
    __shared__ __align__(16) float lsh[64];
    blk_fin64(dsum, dssq, g, b, lsc, lsh, threadIdx.x);
    __syncthreads();
    int t = blockIdx.x*256 + threadIdx.x;
    int e0 = t*4;
    int c0 = e0 & 63;
    float4 v = *(float4*)&X[e0];
    v.x = lrelu(v.x*lsc[c0+0] + lsh[c0+0]);
    v.y = lrelu(v.y*lsc[c0+1] + lsh[c0+1]);
    v.z = lrelu(v.z*lsc[c0+2] + lsh[c0+2]);
    v.w = lrelu(v.w*lsc[c0+3] + lsh[c0+3]);
    *(float4*)&X[e0] = v;
    if (sqn){
        // per-thread squares of cols 4g..4g+3 (g = lane index within 16-thread row group)
        float4 q;
        q.x = v.x*v.x; q.y = v.y*v.y; q.z = v.z*v.z; q.w = v.w*v.w;
        // xor 8,4,2,1 over the 16-thread group == tree steps off 32,16,8,4 of the
        // old kernel (component i pairs col 4g+i with 4g+32+i, etc.)
        #pragma unroll
        for (int off = 8; off >= 1; off >>= 1){
            q.x += __shfl_xor(q.x, off);
            q.y += __shfl_xor(q.y, off);
            q.z += __shfl_xor(q.z, off);
            q.w += __shfl_xor(q.w, off);
        }
        if ((threadIdx.x & 15) == 0){
            int row = e0 >> 6;
            // == tree steps off 2 then 1: (t4(0)+t4(2)) + (t4(1)+t4(3))
            sqn[row] = (q.x + q.z) + (q.y + q.w);
        }
    }
}

// ---------------- in-place bn8+lrelu on out1 (B,256,N), float4, fused L7 finalize ----------------
__global__ void k_bnact8(float* __restrict__ O,
                         const double* __restrict__ dsum, const double* __restrict__ dssq,
                         const float* __restrict__ g, const float* __restrict__ b){
    __shared__ __align__(16) float lsc[256];
    __shared__ __align__(16) float lsh[256];
    blk_finP(dsum, dssq, g, b, lsc, lsh, 256, threadIdx.x);
    __syncthreads();
    int t = blockIdx.x*256 + threadIdx.x;
    int e0 = t*4;
    int oc = (e0 >> 11) & 255;
    float s = lsc[oc], h = lsh[oc];
    float4 v = *(float4*)&O[e0];
    v.x = lrelu(v.x*s + h);
    v.y = lrelu(v.y*s + h);
    v.z = lrelu(v.z*s + h);
    v.w = lrelu(v.w*s + h);
    *(float4*)&O[e0] = v;
}

// ---------------- Gram, up to 2 batches per dispatch: 128x128 tile, 8x8/thread ----------------
__global__ __launch_bounds__(256) void k_gram2(const float* __restrict__ X, float* G0, float* G1, int b0){
    __shared__ __align__(16) float As[32*132];
    __shared__ __align__(16) float Bs[32*132];
    int sub = blockIdx.x >> 8;
    int t   = blockIdx.x & 255;
    const float* Xb = X + (size_t)(b0 + sub)*NN*64;
    float* gram = sub ? G1 : G0;
    int tr = t >> 4, tc = t & 15;
    int tx = threadIdx.x & 15, ty = threadIdx.x >> 4;
    float acc[8][8];
    #pragma unroll
    for (int i = 0; i < 8; i++)
        #pragma unroll
        for (int j = 0; j < 8; j++) acc[i][j] = 0.f;
    for (int kc0 = 0; kc0 < 64; kc0 += 32){
        __syncthreads();
        for (int i = threadIdx.x; i < 128*32; i += 256){
            int k = i & 31, r = i >> 5;
            As[k*132 + r] = Xb[(tr*128 + r)*64 + kc0 + k];
            Bs[k*132 + r] = Xb[(tc*128 + r)*64 + kc0 + k];
        }
        __syncthreads();
        for (int k = 0; k < 32; k++){
            float4 a0 = *(const float4*)&As[k*132 + ty*8];
            float4 a1 = *(const float4*)&As[k*132 + ty*8 + 4];
            float4 b0v = *(const float4*)&Bs[k*132 + tx*8];
            float4 b1v = *(const float4*)&Bs[k*132 + tx*8 + 4];
            float av[8] = {a0.x,a0.y,a0.z,a0.w,a1.x,a1.y,a1.z,a1.w};
            float bv[8] = {b0v.x,b0v.y,b0v.z,b0v.w,b1v.x,b1v.y,b1v.z,b1v.w};
            #pragma unroll
            for (int i = 0; i < 8; i++)
                #pragma unroll
                for (int j = 0; j < 8; j++) acc[i][j] += av[i]*bv[j];
        }
    }
    #pragma unroll
    for (int i = 0; i < 8; i++){
        int row = tr*128 + ty*8 + i;
        *(float4*)&gram[(size_t)row*NN + tc*128 + tx*8]     = make_float4(acc[i][0],acc[i][1],acc[i][2],acc[i][3]);
        *(float4*)&gram[(size_t)row*NN + tc*128 + tx*8 + 4] = make_float4(acc[i][4],acc[i][5],acc[i][6],acc[i][7]);
    }
}

// ---------------- top-20 from gram rows, up to 2 batches per dispatch ----------------
__global__ __launch_bounds__(256) void k_sel2(const float* G0, const float* G1,
                                              const float* __restrict__ sqn, int* __restrict__ idx){
    __shared__ unsigned sval[4*64];
    __shared__ unsigned sidx[4*64];
    int sub = blockIdx.x >> 9;
    int rb  = blockIdx.x & 511;
    const float* gram = sub ? G1 : G0;
    const float* sq   = sqn + sub*NN;
    int lane = threadIdx.x & 63;
    int wid  = threadIdx.x >> 6;
    int n = rb*4 + wid;
    const float* grow = gram + (size_t)n*NN;
    float sn = sq[n];
    unsigned u[32];
    #pragma unroll
    for (int j = 0; j < 32; j++){
        int m = j*64 + lane;
        u[j] = f2sort(2.f*grow[m] - sn - sq[m]);
    }
    topk20(u, lane, sval + wid*64, sidx + wid*64, idx + (sub*NN + n)*KK);
}

// ---------------- C7 precompute ----------------
__global__ __launch_bounds__(256) void k_c7(const float* __restrict__ gmax, const float* __restrict__ w7,
                                            float* __restrict__ C7){
    __shared__ float red[4*8];
    int oc = blockIdx.x;
    int tid = threadIdx.x, lane = tid & 63, wid = tid >> 6;
    float a[8];
    #pragma unroll
    for (int b = 0; b < 8; b++) a[b] = 0.f;
    for (int k = tid; k < 1024; k += 256){
        float wv = w7[oc*1216 + k];
        #pragma unroll
        for (int b = 0; b < 8; b++) a[b] += gmax[b*1024 + k] * wv;
    }
    #pragma unroll
    for (int b = 0; b < 8; b++){
        #pragma unroll
        for (int off = 32; off >= 1; off >>= 1) a[b] += __shfl_xor(a[b], off);
        if (lane == 0) red[wid*8 + b] = a[b];
    }
    __syncthreads();
    if (tid < 8){
        float s = red[tid] + red[8 + tid] + red[16 + tid] + red[24 + tid];
        C7[tid*512 + oc] = s;
    }
}

// ---------------- unified head GEMM: per-mode tile, bf16x3 MFMA ----------------
// MODE2: 128x128   MODE3: 128x64   MODE4: 64x64  (all 1024 blocks = 4/CU)
// MODE4 fuses the L6 BN finalize (512 ch) into a per-block LDS table.
template<int MODE, bool MAXN, int STMODE, typename TST, typename TH7>
__global__ __launch_bounds__(256) void k_head(
    const float* __restrict__ X1, const float* __restrict__ X2, const float* __restrict__ X3,
    const TH7*  __restrict__ H7, const float* __restrict__ C7,
    const double* __restrict__ f_sum, const double* __restrict__ f_ssq,
    const float* __restrict__ f_g, const float* __restrict__ f_b,
    const float* __restrict__ w,
    TST* __restrict__ HST, float* __restrict__ out1t, float* __restrict__ part,
    double* __restrict__ dsum, double* __restrict__ dssq)
{
    constexpr int CIN  = (MODE == 4) ? 512 : 192;
    constexpr int WST  = (MODE == 2) ? 192 : (MODE == 3 ? 1216 : 512);
    constexpr int WOFF = (MODE == 3) ? 1024 : 0;
    constexpr int COUT = (MODE == 2) ? 1024 : (MODE == 3 ? 512 : 256);
    constexpr int BM   = (MODE == 4) ? 64 : 128;
    constexpr int BN   = (MODE == 2) ? 128 : 64;
    constexpr int LOG2NRT = (BM == 64) ? 8 : 7;     // 16384/BM row tiles
    constexpr int RT2  = BM/64;                      // row frags per wave
    constexpr int C2   = BN/16;                      // col frags per wave
    constexpr int RPW  = BM/4;                       // rows per wave
    constexpr int FCH  = (MODE == 4) ? 512 : 1;      // fused-finalize table size
    __shared__ __align__(16) char smem[(BM+BN)*128];
    __shared__ __align__(16) float lscF[FCH];
    __shared__ __align__(16) float lshF[FCH];
    constexpr int AH = 0, AL = BM*64, BH = 2*BM*64, BL = 2*BM*64 + BN*64;
    int tid = threadIdx.x;
    int rt = blockIdx.x & ((1 << LOG2NRT) - 1);
    int ct = blockIdx.x >> LOG2NRT;
    int row0 = rt * BM;
    int col0 = ct * BN;
    int b = row0 >> 11;
    int wv = tid >> 6, l = tid & 63;
    int rl = l & 15, g = l >> 4;

    if (MODE == 4){
        blk_finP(f_sum, f_ssq, f_g, f_b, lscF, lshF, 512, tid);
        __syncthreads();
    }

    f32x4 acc[RT2][C2];
    #pragma unroll
    for (int i = 0; i < RT2; i++)
        #pragma unroll
        for (int j = 0; j < C2; j++) acc[i][j] = (f32x4){0.f,0.f,0.f,0.f};

    for (int s = 0; s < CIN/32; s++){
        int cg0 = s*32;
        __syncthreads();
        // ---- stage A (BM rows x 32 k), 8 elems/thread/iter ----
        #pragma unroll
        for (int it = 0; it < BM/64; it++){
            int i = tid + it*256;
            int r = i >> 2, kg = i & 3;
            float v[8];
            if (MODE == 4){
                float4 s0 = *(float4*)&lscF[cg0 + kg*8];
                float4 s1 = *(float4*)&lscF[cg0 + kg*8 + 4];
                float4 h0 = *(float4*)&lshF[cg0 + kg*8];
                float4 h1 = *(float4*)&lshF[cg0 + kg*8 + 4];
                float ss[8] = {s0.x,s0.y,s0.z,s0.w,s1.x,s1.y,s1.z,s1.w};
                float hh[8] = {h0.x,h0.y,h0.z,h0.w,h1.x,h1.y,h1.z,h1.w};
                if constexpr (sizeof(TH7) == 2){
                    union { uint4 q; unsigned short us[8]; } raw;
                    raw.q = *(const uint4*)&H7[(size_t)(row0 + r)*512 + cg0 + kg*8];
                    #pragma unroll
                    for (int e = 0; e < 8; e++)
                        v[e] = lrelu(__uint_as_float((unsigned)raw.us[e] << 16)*ss[e] + hh[e]);
                } else {
                    float4 a0 = *(const float4*)&H7[(size_t)(row0 + r)*512 + cg0 + kg*8];
                    float4 a1 = *(const float4*)&H7[(size_t)(row0 + r)*512 + cg0 + kg*8 + 4];
                    float av[8] = {a0.x,a0.y,a0.z,a0.w,a1.x,a1.y,a1.z,a1.w};
                    #pragma unroll
                    for (int e = 0; e < 8; e++) v[e] = lrelu(av[e]*ss[e] + hh[e]);
                }
            } else {
                const float* S = (cg0 < 64) ? X1 : (cg0 < 128 ? X2 : X3);
                int co = cg0 & 63;
                float4 a0 = *(const float4*)&S[(row0 + r)*64 + co + kg*8];
                float4 a1 = *(const float4*)&S[(row0 + r)*64 + co + kg*8 + 4];
                v[0]=a0.x; v[1]=a0.y; v[2]=a0.z; v[3]=a0.w;
                v[4]=a1.x; v[5]=a1.y; v[6]=a1.z; v[7]=a1.w;
            }
            union { bf16 h[8]; uint4 u; } ph, pl;
            #pragma unroll
            for (int e = 0; e < 8; e++) split2b(v[e], ph.h[e], pl.h[e]);
            *(uint4*)(smem + AH + r*64 + kg*16) = ph.u;
            *(uint4*)(smem + AL + r*64 + kg*16) = pl.u;
        }
        // ---- stage B (BN cols x 32 k) ----
        #pragma unroll
        for (int it = 0; it < BN/64; it++){
            int i = tid + it*256;
            int n = i >> 2, kg = i & 3;
            float4 b0 = *(const float4*)&w[(size_t)(col0 + n)*WST + WOFF + cg0 + kg*8];
            float4 b1 = *(const float4*)&w[(size_t)(col0 + n)*WST + WOFF + cg0 + kg*8 + 4];
            float v[8] = {b0.x,b0.y,b0.z,b0.w,b1.x,b1.y,b1.z,b1.w};
            union { bf16 h[8]; uint4 u; } ph, pl;
            #pragma unroll
            for (int e = 0; e < 8; e++) split2b(v[e], ph.h[e], pl.h[e]);
            *(uint4*)(smem + BH + n*64 + kg*16) = ph.u;
            *(uint4*)(smem + BL + n*64 + kg*16) = pl.u;
        }
        __syncthreads();
        #pragma unroll
        for (int rt2 = 0; rt2 < RT2; rt2++){
            int ar = (wv*RPW + rt2*16 + rl)*64 + g*16;
            bf16x8 ah = *(const bf16x8*)(smem + AH + ar);
            bf16x8 al = *(const bf16x8*)(smem + AL + ar);
            #pragma unroll
            for (int c2 = 0; c2 < C2; c2++){
                int br = (c2*16 + rl)*64 + g*16;
                bf16x8 bh = *(const bf16x8*)(smem + BH + br);
                bf16x8 bl = *(const bf16x8*)(smem + BL + br);
                acc[rt2][c2] = __builtin_amdgcn_mfma_f32_16x16x32_bf16(al, bh, acc[rt2][c2], 0, 0, 0);
                acc[rt2][c2] = __builtin_amdgcn_mfma_f32_16x16x32_bf16(ah, bl, acc[rt2][c2], 0, 0, 0);
                acc[rt2][c2] = __builtin_amdgcn_mfma_f32_16x16x32_bf16(ah, bh, acc[rt2][c2], 0, 0, 0);
            }
        }
    }
    // lane's element (rt2,c2,rr): row = row0 + wv*RPW + rt2*16 + g*4 + rr ; col = col0 + c2*16 + rl
    if (MODE == 3){
        #pragma unroll
        for (int c2 = 0; c2 < C2; c2++){
            float c7 = C7[b*512 + col0 + c2*16 + rl];
            #pragma unroll
            for (int rt2 = 0; rt2 < RT2; rt2++)
                #pragma unroll
                for (int rr = 0; rr < 4; rr++) acc[rt2][c2][rr] += c7;
        }
    }
    if (STMODE == 1){
        #pragma unroll
        for (int rt2 = 0; rt2 < RT2; rt2++)
            #pragma unroll
            for (int c2 = 0; c2 < C2; c2++){
                int colg = col0 + c2*16 + rl;
                int rowg = row0 + wv*RPW + rt2*16 + g*4;
                #pragma unroll
                for (int rr = 0; rr < 4; rr++)
                    HST[(size_t)(rowg + rr)*COUT + colg] = (TST)acc[rt2][c2][rr];
            }
    } else if (STMODE == 2){
        int nb = (row0 & (NN-1)) + wv*RPW + g*4;
        #pragma unroll
        for (int rt2 = 0; rt2 < RT2; rt2++)
            #pragma unroll
            for (int c2 = 0; c2 < C2; c2++){
                float* o = out1t + b*256*NN + (size_t)(col0 + c2*16 + rl)*NN + nb + rt2*16;
                *(float4*)o = make_float4(acc[rt2][c2][0], acc[rt2][c2][1], acc[rt2][c2][2], acc[rt2][c2][3]);
            }
    }
    __syncthreads();
    float* sbuf = (float*)smem;
    float* qbuf = (float*)smem + 16*BN;
    float* mbuf = (float*)smem + 32*BN;
    int gi = wv*4 + g;
    #pragma unroll
    for (int c2 = 0; c2 < C2; c2++){
        float sv = 0.f, qv = 0.f, mv = -INFINITY;
        #pragma unroll
        for (int rt2 = 0; rt2 < RT2; rt2++)
            #pragma unroll
            for (int rr = 0; rr < 4; rr++){
                float v = acc[rt2][c2][rr];
                sv += v;
                qv += v*v;
                if (MAXN) mv = fmaxf(mv, v);
            }
        sbuf[gi*BN + c2*16 + rl] = sv;
        qbuf[gi*BN + c2*16 + rl] = qv;
        if (MAXN) mbuf[gi*BN + c2*16 + rl] = mv;
    }
    __syncthreads();
    if (tid < BN){
        double t = 0.0;
        #pragma unroll
        for (int k = 0; k < 16; k++) t += (double)sbuf[k*BN + tid];
        atomicAdd(&dsum[col0 + tid], t);
        if (MAXN){
            float mm = -INFINITY;
            #pragma unroll
            for (int k = 0; k < 16; k++) mm = fmaxf(mm, mbuf[k*BN + tid]);
            part[rt*1024 + col0 + tid] = mm;
        }
    } else if (tid < 2*BN){
        int c = tid - BN;
        double t = 0.0;
        #pragma unroll
        for (int k = 0; k < 16; k++) t += (double)qbuf[k*BN + c];
        atomicAdd(&dssq[col0 + c], t);
    }
}

// ---------------- reduce partial maxes, fused L5 finalize + bn6+lrelu ----------------
__global__ void k_gmax_fin(const float* __restrict__ part,
                           const double* __restrict__ dsum, const double* __restrict__ dssq,
                           const float* __restrict__ g, const float* __restrict__ b,
                           float* __restrict__ gmax){
    __shared__ float lsc[1024];
    __shared__ float lsh[1024];
    blk_finP(dsum, dssq, g, b, lsc, lsh, 1024, threadIdx.x);
    __syncthreads();
    int t = blockIdx.x*256 + threadIdx.x;
    int bb2 = t >> 10, c = t & 1023;
    float m = -INFINITY;
    #pragma unroll
    for (int k = 0; k < 16; k++) m = fmaxf(m, part[(bb2*16 + k)*1024 + c]);
    gmax[t] = lrelu(m*lsc[c] + lsh[c]);
}

// ---------------- tier C: fused L7 finalize + BN8+lrelu + transpose from H8 bf16 ----------------
__global__ __launch_bounds__(256) void k_final_b(const bf16* __restrict__ H8,
                                                 const double* __restrict__ dsum, const double* __restrict__ dssq,
                                                 const float* __restrict__ g, const float* __restrict__ b,
                                                 float* __restrict__ out1){
    __shared__ float tile[64*65];
    __shared__ float lsc[256];
    __shared__ float lsh[256];
    blk_finP(dsum, dssq, g, b, lsc, lsh, 256, threadIdx.x);
    __syncthreads();
    int bi = blockIdx.x;
    int bb2 = bi / 128;
    int r  = bi % 128;
    int nt = r >> 2, ot = r & 3;
    for (int i = threadIdx.x; i < 64*64; i += 256){
        int o = i & 63, nl = i >> 6;
        float v = (float)H8[((bb2*NN) + nt*64 + nl)*256 + ot*64 + o];
        int oc = ot*64 + o;
        tile[o*65 + nl] = lrelu(v*lsc[oc] + lsh[oc]);
    }
    __syncthreads();
    for (int i = threadIdx.x; i < 64*64; i += 256){
        int nl = i & 63, o = i >> 6;
        out1[bb2*256*NN + (ot*64 + o)*NN + nt*64 + nl] = tile[o*65 + nl];
    }
}

// ---------------- host launcher ----------------
extern "C" void kernel_launch(void* const* d_in, const int* in_sizes, int n_in,
                              void* d_out, int out_size, void* d_ws, size_t ws_size,
                              hipStream_t stream){
    const float* x = (const float*)d_in[0];
    const float *w[8], *g[8], *bb[8];
    for (int i = 0; i < 8; i++){
        w[i]  = (const float*)d_in[1 + i*3];
        g[i]  = (const float*)d_in[2 + i*3];
        bb[i] = (const float*)d_in[3 + i*3];
    }
    float* ws  = (float*)d_ws;
    float* X1  = ws + OFF_X1;
    float* X2  = ws + OFF_X2;
    float* X3  = ws + OFF_X3;
    float* SQN = ws + OFF_SQN;
    float* GMAX= ws + OFF_GMAX;
    float* PART= ws + OFF_PART;
    float* C7  = ws + OFF_PART + 131072;
    double* SLOTS = (double*)(ws + OFF_PART + 135168);   // 20480 doubles (L0..L4 slot stats)
    double* DS    = SLOTS + 5*2*64*NSLOT;                // 4224 doubles, contiguous after SLOTS
    int*   IDX = (int*)(ws + OFF_IDX);

    float* out0 = (float*)d_out;
    float* out1 = out0 + BB*NN*CC;
    float* P    = out1;
    float* Q    = out1 + 1048576;
    float* GRAM0= out1;
    float* GRAM1= ws + BASE_END;
    bool dualGram = ws_size >= (size_t)(BASE_END + 4194304)*4;

    const int chs[8]   = {64,64,64,64,64,1024,512,256};
    const int base[8]  = {0,128,256,384,512,640,2688,3712};
    double *SUMp[8], *SSQp[8];
    for (int L = 0; L < 8; L++){
        if (L < 5){
            SUMp[L] = SLOTS + L*2*64*NSLOT;
            SSQp[L] = SLOTS + L*2*64*NSLOT + 64*NSLOT;
        } else {
            SUMp[L] = DS + base[L];
            SSQp[L] = DS + base[L] + chs[L];
        }
    }

    // single contiguous memset: SLOTS (20480) + DS (4224) doubles
    hipMemsetAsync(SLOTS, 0, (size_t)(5*2*64*NSLOT + 4224)*sizeof(double), stream);

    // ---- stage 1 ----
    k_knn3<<<BB*NN/4,256,0,stream>>>(x, IDX);
    k_pq9<<<512,256,0,stream>>>(x, w[0], P, Q, out0);
    k_hstats<false><<<4096,256,0,stream>>>(P, Q, IDX, nullptr, SUMp[0], SSQp[0]);
    k_edgegemm<<<4096,256,0,stream>>>(P, Q, IDX, SUMp[0], SSQp[0], g[0], bb[0], w[1], X1, SUMp[1], SSQp[1]);
    k_bnact<<<1024,256,0,stream>>>(X1, SUMp[1], SSQp[1], g[1], bb[1], SQN);

    // ---- stage 2 & 3 knn + edge ----
    for (int stage = 0; stage < 2; stage++){
        float* Xs = (stage == 0) ? X1 : X2;
        if (dualGram){
            for (int pr = 0; pr < 4; pr++){
                k_gram2<<<512,256,0,stream>>>(Xs, GRAM0, GRAM1, pr*2);
                k_sel2<<<1024,256,0,stream>>>(GRAM0, GRAM1, SQN + pr*2*NN, IDX + pr*2*NN*KK);
            }
        } else {
            for (int b = 0; b < BB; b++){
                k_gram2<<<256,256,0,stream>>>(Xs, GRAM0, GRAM0, b);
                k_sel2<<<512,256,0,stream>>>(GRAM0, GRAM0, SQN + b*NN, IDX + b*NN*KK);
            }
        }
        if (stage == 0){
            k_pq64<<<512,256,0,stream>>>(X1, w[2], P, Q);
            k_hstats<false><<<4096,256,0,stream>>>(P, Q, IDX, nullptr, SUMp[2], SSQp[2]);
            k_edgegemm<<<4096,256,0,stream>>>(P, Q, IDX, SUMp[2], SSQp[2], g[2], bb[2], w[3], X2, SUMp[3], SSQp[3]);
            k_bnact<<<1024,256,0,stream>>>(X2, SUMp[3], SSQp[3], g[3], bb[3], SQN);
        } else {
            k_pq64<<<512,256,0,stream>>>(X2, w[4], P, Q);
            k_hstats<true><<<4096,256,0,stream>>>(P, Q, IDX, X3, SUMp[4], SSQp[4]);
            k_bnact<<<1024,256,0,stream>>>(X3, SUMp[4], SSQp[4], g[4], bb[4], nullptr);
        }
    }

    // ---- layer 6 + global max ----
    k_head<2,true,0,float,float><<<1024,256,0,stream>>>(
        X1,X2,X3,(const float*)nullptr,nullptr,nullptr,nullptr,nullptr,nullptr,w[5],
        (float*)nullptr,nullptr,PART,SUMp[5],SSQp[5]);
    k_gmax_fin<<<32,256,0,stream>>>(PART, SUMp[5], SSQp[5], g[5], bb[5], GMAX);
    k_c7<<<512,256,0,stream>>>(GMAX, w[6], C7);

    // ---- layers 7/8, tiered by ws_size ----
    if (ws_size >= (size_t)12161536*4){
        float* H7f = ws + BASE_END;
        k_head<3,false,1,float,float><<<1024,256,0,stream>>>(
            X1,X2,X3,(const float*)nullptr,C7,nullptr,nullptr,nullptr,nullptr,w[6],
            H7f,nullptr,nullptr,SUMp[6],SSQp[6]);
        k_head<4,false,2,float,float><<<1024,256,0,stream>>>(
            nullptr,nullptr,nullptr,H7f,nullptr,SUMp[6],SSQp[6],g[6],bb[6],w[7],
            (float*)nullptr,out1,nullptr,SUMp[7],SSQp[7]);
        k_bnact8<<<4096,256,0,stream>>>(out1, SUMp[7], SSQp[7], g[7], bb[7]);
    } else if (ws_size >= (size_t)7967232*4){
        bf16* H7b = (bf16*)(ws + BASE_END);
        k_head<3,false,1,bf16,float><<<1024,256,0,stream>>>(
            X1,X2,X3,(const float*)nullptr,C7,nullptr,nullptr,nullptr,nullptr,w[6],
            H7b,nullptr,nullptr,SUMp[6],SSQp[6]);
        k_head<4,false,2,float,bf16><<<1024,256,0,stream>>>(
            nullptr,nullptr,nullptr,H7b,nullptr,SUMp[6],SSQp[6],g[6],bb[6],w[7],
            (float*)nullptr,out1,nullptr,SUMp[7],SSQp[7]);
        k_bnact8<<<4096,256,0,stream>>>(out1, SUMp[7], SSQp[7], g[7], bb[7]);
    } else {
        bf16* H7b = (bf16*)out1;
        bf16* H8b = (bf16*)(ws + OFF_X1);
        k_head<3,false,1,bf16,float><<<1024,256,0,stream>>>(
            X1,X2,X3,(const float*)nullptr,C7,nullptr,nullptr,nullptr,nullptr,w[6],
            H7b,nullptr,nullptr,SUMp[6],SSQp[6]);
        k_head<4,false,1,bf16,bf16><<<1024,256,0,stream>>>(
            nullptr,nullptr,nullptr,H7b,nullptr,SUMp[6],SSQp[6],g[6],bb[6],w[7],
            H8b,nullptr,nullptr,SUMp[7],SSQp[7]);
        k_final_b<<<1024,256,0,stream>>>(H8b, SUMp[7], SSQp[7], g[7], bb[7], out1);
    }
}